// Round 4
// baseline (275.053 us; speedup 1.0000x reference)
//
#include <hip/hip_runtime.h>

#define BATCH 4
#define SEQ   2048
#define CDIM  1024
#define NHEAD 16
#define HDIM  64
#define BH    (BATCH * NHEAD)   // 64
#define MROWS (BATCH * SEQ)     // 8192

typedef __attribute__((ext_vector_type(8))) short  short8;
typedef __attribute__((ext_vector_type(4))) float  floatx4;

#define MFMA_BF16(a, b, c) __builtin_amdgcn_mfma_f32_16x16x32_bf16((a), (b), (c), 0, 0, 0)

// async global->LDS, 16B per lane; LDS dest is wave-uniform base + lane*16
#define GLOAD16(g, l) __builtin_amdgcn_global_load_lds( \
    (__attribute__((address_space(1))) void*)(g),       \
    (__attribute__((address_space(3))) void*)(l), 16, 0, 0)

__device__ __forceinline__ unsigned short f2bf(float f) {
    union { float f; unsigned u; } v; v.f = f;
    unsigned u = v.u;
    return (unsigned short)((u + 0x7FFFu + ((u >> 16) & 1u)) >> 16);
}

__device__ __forceinline__ float fast_exp2(float x) {
#if __has_builtin(__builtin_amdgcn_exp2f)
    return __builtin_amdgcn_exp2f(x);
#else
    return exp2f(x);
#endif
}

// pack two fp32 -> two bf16, truncating (bias cancels in softmax normalization)
__device__ __forceinline__ unsigned pack_bf16_trunc(float a, float b) {
    union { float f; unsigned u; } ua, ub;
    ua.f = a; ub.f = b;
    return __builtin_amdgcn_perm(ub.u, ua.u, 0x07060302u);
}

// ---------------------------------------------------------------------------
// fp32 -> bf16 elementwise convert (x). 4 elems/thread.
// ---------------------------------------------------------------------------
__global__ __launch_bounds__(256) void conv_bf16_kernel(
    const float* __restrict__ in, unsigned short* __restrict__ out)
{
    int i = (blockIdx.x * 256 + threadIdx.x) * 4;
    float4 v = *(const float4*)(in + i);
    ushort4 o;
    o.x = f2bf(v.x); o.y = f2bf(v.y); o.z = f2bf(v.z); o.w = f2bf(v.w);
    *(ushort4*)(out + i) = o;
}

// ---------------------------------------------------------------------------
// fp32 [K][N] -> bf16 transposed [N][K] (weights). 64x64 LDS tiles.
// ---------------------------------------------------------------------------
__global__ __launch_bounds__(256) void conv_wt_kernel(
    const float* __restrict__ in, unsigned short* __restrict__ out, int K, int N)
{
    __shared__ float T[64][68];
    const int k0 = blockIdx.y * 64, n0 = blockIdx.x * 64;
    const int tid = threadIdx.x;
    const int r = tid >> 4, c4 = (tid & 15) * 4;
    #pragma unroll
    for (int i = 0; i < 4; ++i) {
        int row = r + i * 16;
        float4 v = *(const float4*)(in + (size_t)(k0 + row) * N + n0 + c4);
        T[row][c4 + 0] = v.x; T[row][c4 + 1] = v.y;
        T[row][c4 + 2] = v.z; T[row][c4 + 3] = v.w;
    }
    __syncthreads();
    #pragma unroll
    for (int i = 0; i < 4; ++i) {
        int nrow = r + i * 16;
        ushort4 o;
        o.x = f2bf(T[c4 + 0][nrow]); o.y = f2bf(T[c4 + 1][nrow]);
        o.z = f2bf(T[c4 + 2][nrow]); o.w = f2bf(T[c4 + 3][nrow]);
        *(ushort4*)(out + (size_t)(n0 + nrow) * K + k0 + c4) = o;
    }
}

// ---------------------------------------------------------------------------
// QKV GEMM: 256x256 tile, BK=64, 512 thr = 8 waves (2M x 4N), 8-phase
// schedule with counted vmcnt (never 0 in main loop), LDS XOR-chunk swizzle
// (applied on the global source side; global_load_lds dest stays linear),
// setprio around each 16-MFMA cluster.  [verified passing: round 1]
// ---------------------------------------------------------------------------
__global__ __launch_bounds__(512, 2) void qkv_mfma_kernel(
    const unsigned short* __restrict__ A,    // xb [8192][1024]
    const unsigned short* __restrict__ Bt,   // Wat [3072][1024]
    const float* __restrict__ bias,          // [3072]
    unsigned short* __restrict__ Qo,         // [BH][T][64]
    unsigned short* __restrict__ Ko,         // [BH][T][64]
    unsigned short* __restrict__ Vo)         // [BH][64][T]
{
    __shared__ __align__(16) unsigned short L[2 * 32768];   // 128 KB

    const int tid = threadIdx.x;
    const int m0 = blockIdx.y * 256, n0 = blockIdx.x * 256;
    const int w = tid >> 6, lane = tid & 63;
    const int wr = w >> 2, wc = w & 3;        // 2M x 4N
    const int lm = lane & 15, kg = lane >> 4;
    const int sw = lm & 7;                    // read-side XOR swizzle key

    floatx4 acc[2][4][2][2];
    const floatx4 zf = {0.f, 0.f, 0.f, 0.f};
    #pragma unroll
    for (int a = 0; a < 2; ++a)
        #pragma unroll
        for (int b = 0; b < 4; ++b)
            #pragma unroll
            for (int c = 0; c < 2; ++c)
                #pragma unroll
                for (int d = 0; d < 2; ++d) acc[a][b][c][d] = zf;

    short8 af[4][2], bf[2][2];

#define QSTAGE_A(B_, H_, KT_) do {                                            \
    unsigned short* _l = (unsigned short*)L + (B_) * 32768 + (H_) * 8192;     \
    _Pragma("unroll")                                                         \
    for (int _i = 0; _i < 2; ++_i) {                                          \
        int _s = _i * 512 + tid, _r = _s >> 3, _c = _s & 7;                   \
        GLOAD16(A + (size_t)(m0 + (H_) * 128 + _r) * CDIM + (KT_) * 64        \
                   + ((_c ^ (_r & 7)) * 8), _l + _s * 8);                     \
    } } while (0)

#define QSTAGE_B(B_, H_, KT_) do {                                            \
    unsigned short* _l = (unsigned short*)L + (B_) * 32768 + 16384 + (H_) * 8192; \
    _Pragma("unroll")                                                         \
    for (int _i = 0; _i < 2; ++_i) {                                          \
        int _s = _i * 512 + tid, _r = _s >> 3, _c = _s & 7;                   \
        GLOAD16(Bt + (size_t)(n0 + (H_) * 128 + _r) * CDIM + (KT_) * 64       \
                   + ((_c ^ (_r & 7)) * 8), _l + _s * 8);                     \
    } } while (0)

#define QLOAD_A(B_, H_) do {                                                  \
    const unsigned short* _p = (const unsigned short*)L + (B_) * 32768 + (H_) * 8192; \
    _Pragma("unroll")                                                         \
    for (int _m = 0; _m < 4; ++_m) {                                          \
        int _row = wr * 64 + _m * 16 + lm;                                    \
        _Pragma("unroll")                                                     \
        for (int _k = 0; _k < 2; ++_k)                                        \
            af[_m][_k] = *(const short8*)(_p + _row * 64                      \
                          + (((_k * 4 + kg) ^ sw) * 8));                      \
    } } while (0)

#define QLOAD_B(B_, H_) do {                                                  \
    const unsigned short* _p = (const unsigned short*)L + (B_) * 32768 + 16384 + (H_) * 8192; \
    _Pragma("unroll")                                                         \
    for (int _n = 0; _n < 2; ++_n) {                                          \
        int _row = wc * 32 + _n * 16 + lm;                                    \
        _Pragma("unroll")                                                     \
        for (int _k = 0; _k < 2; ++_k)                                        \
            bf[_n][_k] = *(const short8*)(_p + _row * 64                      \
                          + (((_k * 4 + kg) ^ sw) * 8));                      \
    } } while (0)

#define QMFMA(HH_, HP_) do {                                                  \
    _Pragma("unroll") for (int _k = 0; _k < 2; ++_k)                          \
    _Pragma("unroll") for (int _m = 0; _m < 4; ++_m)                          \
    _Pragma("unroll") for (int _n = 0; _n < 2; ++_n)                          \
        acc[HH_][_m][HP_][_n] =                                               \
            MFMA_BF16(af[_m][_k], bf[_n][_k], acc[HH_][_m][HP_][_n]);         \
    } while (0)

#define QPHASE(HH_, HP_, LA_, LB_, STAGE_, VM_) do {                          \
    if (LA_) QLOAD_A(buf, HH_);                                               \
    if (LB_) QLOAD_B(buf, HP_);                                               \
    STAGE_;                                                                   \
    asm volatile("s_waitcnt vmcnt(" #VM_ ")" ::: "memory");                   \
    __builtin_amdgcn_s_barrier();                                             \
    asm volatile("s_waitcnt lgkmcnt(0)" ::: "memory");                        \
    __builtin_amdgcn_sched_barrier(0);                                        \
    __builtin_amdgcn_s_setprio(1);                                            \
    QMFMA(HH_, HP_);                                                          \
    __builtin_amdgcn_s_setprio(0);                                            \
    __builtin_amdgcn_s_barrier();                                             \
    __builtin_amdgcn_sched_barrier(0);                                        \
    } while (0)

    // prologue: tile 0, halves in first-use order; drain to 4 -> A0,B0 landed
    QSTAGE_A(0, 0, 0); QSTAGE_B(0, 0, 0); QSTAGE_B(0, 1, 0); QSTAGE_A(0, 1, 0);
    asm volatile("s_waitcnt vmcnt(4)" ::: "memory");
    __builtin_amdgcn_s_barrier();

    #pragma unroll 1
    for (int t = 0; t < CDIM / 64 - 1; ++t) {
        const int buf = t & 1, nb = buf ^ 1;
        QPHASE(0, 0, 1, 1, QSTAGE_A(nb, 0, t + 1), 4);
        QPHASE(0, 1, 0, 1, QSTAGE_B(nb, 0, t + 1), 4);
        QPHASE(1, 1, 1, 0, QSTAGE_B(nb, 1, t + 1), 4);
        QPHASE(1, 0, 0, 1, QSTAGE_A(nb, 1, t + 1), 4);
    }
    {   // last tile: no staging; drain 2 -> 0
        const int buf = (CDIM / 64 - 1) & 1;
        QPHASE(0, 0, 1, 1, ((void)0), 2);
        QPHASE(0, 1, 0, 1, ((void)0), 0);
        QPHASE(1, 1, 1, 0, ((void)0), 0);
        QPHASE(1, 0, 0, 1, ((void)0), 0);
    }

#undef QPHASE
#undef QMFMA
#undef QLOAD_B
#undef QLOAD_A
#undef QSTAGE_B
#undef QSTAGE_A

    // epilogue: C frag (hh,mt,hp,nt): row = m0+hh*128+wr*64+mt*16+kg*4+r,
    //                                 col = n0+hp*128+wc*32+nt*16+lm
    #pragma unroll
    for (int hp = 0; hp < 2; ++hp) {
        #pragma unroll
        for (int nt = 0; nt < 2; ++nt) {
            int col = n0 + hp * 128 + wc * 32 + nt * 16 + lm;
            float bv = bias[col];
            int which = col >> 10;
            int c1 = col & 1023;
            int h = c1 >> 6, d = c1 & 63;
            #pragma unroll
            for (int hh = 0; hh < 2; ++hh) {
                #pragma unroll
                for (int mt = 0; mt < 4; ++mt) {
                    int m = m0 + hh * 128 + wr * 64 + mt * 16 + kg * 4;
                    int b = m >> 11;
                    int tt = m & 2047;           // tt..tt+3 contiguous
                    int bh = b * NHEAD + h;
                    floatx4 a = acc[hh][mt][hp][nt];
                    if (which == 2) {
                        ushort4 o;
                        o.x = f2bf(a[0] + bv);
                        o.y = f2bf(a[1] + bv);
                        o.z = f2bf(a[2] + bv);
                        o.w = f2bf(a[3] + bv);
                        *(ushort4*)(Vo + ((size_t)bh * 64 + d) * SEQ + tt) = o;
                    } else {
                        unsigned short* dst = (which == 0) ? Qo : Ko;
                        float qs = (which == 0) ? 0.18033688011112042f : 1.0f;
                        #pragma unroll
                        for (int r = 0; r < 4; ++r)
                            dst[((size_t)bh * SEQ + tt + r) * 64 + d] =
                                f2bf((a[r] + bv) * qs);
                    }
                }
            }
        }
    }
}

// ---------------------------------------------------------------------------
// Proj GEMM: same verified 256x256 8-phase template as qkv (identical tile,
// BK, wave geometry, stage order, vmcnt numbers), linear fp32+bias epilogue.
// Grid (CDIM/256, MROWS/256) = (4, 32) = 128 blocks.
// ---------------------------------------------------------------------------
__global__ __launch_bounds__(512, 2) void proj_mfma_kernel(
    const unsigned short* __restrict__ A,    // Yb [8192][1024]
    const unsigned short* __restrict__ Bt,   // Wpt [1024][1024]
    const float* __restrict__ bias,          // [1024]
    float* __restrict__ out)                 // [8192][1024] fp32
{
    __shared__ __align__(16) unsigned short L[2 * 32768];   // 128 KB

    const int tid = threadIdx.x;
    const int m0 = blockIdx.y * 256, n0 = blockIdx.x * 256;
    const int w = tid >> 6, lane = tid & 63;
    const int wr = w >> 2, wc = w & 3;        // 2M x 4N
    const int lm = lane & 15, kg = lane >> 4;
    const int sw = lm & 7;                    // read-side XOR swizzle key

    floatx4 acc[2][4][2][2];
    const floatx4 zf = {0.f, 0.f, 0.f, 0.f};
    #pragma unroll
    for (int a = 0; a < 2; ++a)
        #pragma unroll
        for (int b = 0; b < 4; ++b)
            #pragma unroll
            for (int c = 0; c < 2; ++c)
                #pragma unroll
                for (int d = 0; d < 2; ++d) acc[a][b][c][d] = zf;

    short8 af[4][2], bf[2][2];

#define PSTAGE_A(B_, H_, KT_) do {                                            \
    unsigned short* _l = (unsigned short*)L + (B_) * 32768 + (H_) * 8192;     \
    _Pragma("unroll")                                                         \
    for (int _i = 0; _i < 2; ++_i) {                                          \
        int _s = _i * 512 + tid, _r = _s >> 3, _c = _s & 7;                   \
        GLOAD16(A + (size_t)(m0 + (H_) * 128 + _r) * CDIM + (KT_) * 64        \
                   + ((_c ^ (_r & 7)) * 8), _l + _s * 8);                     \
    } } while (0)

#define PSTAGE_B(B_, H_, KT_) do {                                            \
    unsigned short* _l = (unsigned short*)L + (B_) * 32768 + 16384 + (H_) * 8192; \
    _Pragma("unroll")                                                         \
    for (int _i = 0; _i < 2; ++_i) {                                          \
        int _s = _i * 512 + tid, _r = _s >> 3, _c = _s & 7;                   \
        GLOAD16(Bt + (size_t)(n0 + (H_) * 128 + _r) * CDIM + (KT_) * 64       \
                   + ((_c ^ (_r & 7)) * 8), _l + _s * 8);                     \
    } } while (0)

#define PLOAD_A(B_, H_) do {                                                  \
    const unsigned short* _p = (const unsigned short*)L + (B_) * 32768 + (H_) * 8192; \
    _Pragma("unroll")                                                         \
    for (int _m = 0; _m < 4; ++_m) {                                          \
        int _row = wr * 64 + _m * 16 + lm;                                    \
        _Pragma("unroll")                                                     \
        for (int _k = 0; _k < 2; ++_k)                                        \
            af[_m][_k] = *(const short8*)(_p + _row * 64                      \
                          + (((_k * 4 + kg) ^ sw) * 8));                      \
    } } while (0)

#define PLOAD_B(B_, H_) do {                                                  \
    const unsigned short* _p = (const unsigned short*)L + (B_) * 32768 + 16384 + (H_) * 8192; \
    _Pragma("unroll")                                                         \
    for (int _n = 0; _n < 2; ++_n) {                                          \
        int _row = wc * 32 + _n * 16 + lm;                                    \
        _Pragma("unroll")                                                     \
        for (int _k = 0; _k < 2; ++_k)                                        \
            bf[_n][_k] = *(const short8*)(_p + _row * 64                      \
                          + (((_k * 4 + kg) ^ sw) * 8));                      \
    } } while (0)

#define PMFMA(HH_, HP_) do {                                                  \
    _Pragma("unroll") for (int _k = 0; _k < 2; ++_k)                          \
    _Pragma("unroll") for (int _m = 0; _m < 4; ++_m)                          \
    _Pragma("unroll") for (int _n = 0; _n < 2; ++_n)                          \
        acc[HH_][_m][HP_][_n] =                                               \
            MFMA_BF16(af[_m][_k], bf[_n][_k], acc[HH_][_m][HP_][_n]);         \
    } while (0)

#define PPHASE(HH_, HP_, LA_, LB_, STAGE_, VM_) do {                          \
    if (LA_) PLOAD_A(buf, HH_);                                               \
    if (LB_) PLOAD_B(buf, HP_);                                               \
    STAGE_;                                                                   \
    asm volatile("s_waitcnt vmcnt(" #VM_ ")" ::: "memory");                   \
    __builtin_amdgcn_s_barrier();                                             \
    asm volatile("s_waitcnt lgkmcnt(0)" ::: "memory");                        \
    __builtin_amdgcn_sched_barrier(0);                                        \
    __builtin_amdgcn_s_setprio(1);                                            \
    PMFMA(HH_, HP_);                                                          \
    __builtin_amdgcn_s_setprio(0);                                            \
    __builtin_amdgcn_s_barrier();                                             \
    __builtin_amdgcn_sched_barrier(0);                                        \
    } while (0)

    PSTAGE_A(0, 0, 0); PSTAGE_B(0, 0, 0); PSTAGE_B(0, 1, 0); PSTAGE_A(0, 1, 0);
    asm volatile("s_waitcnt vmcnt(4)" ::: "memory");
    __builtin_amdgcn_s_barrier();

    #pragma unroll 1
    for (int t = 0; t < CDIM / 64 - 1; ++t) {
        const int buf = t & 1, nb = buf ^ 1;
        PPHASE(0, 0, 1, 1, PSTAGE_A(nb, 0, t + 1), 4);
        PPHASE(0, 1, 0, 1, PSTAGE_B(nb, 0, t + 1), 4);
        PPHASE(1, 1, 1, 0, PSTAGE_B(nb, 1, t + 1), 4);
        PPHASE(1, 0, 0, 1, PSTAGE_A(nb, 1, t + 1), 4);
    }
    {   // last tile: no staging; drain 2 -> 0
        const int buf = (CDIM / 64 - 1) & 1;
        PPHASE(0, 0, 1, 1, ((void)0), 2);
        PPHASE(0, 1, 0, 1, ((void)0), 0);
        PPHASE(1, 1, 1, 0, ((void)0), 0);
        PPHASE(1, 0, 0, 1, ((void)0), 0);
    }

#undef PPHASE
#undef PMFMA
#undef PLOAD_B
#undef PLOAD_A
#undef PSTAGE_B
#undef PSTAGE_A

    // epilogue: out[row][col] = acc + bias (fp32)
    #pragma unroll
    for (int hp = 0; hp < 2; ++hp) {
        #pragma unroll
        for (int nt = 0; nt < 2; ++nt) {
            int col = n0 + hp * 128 + wc * 32 + nt * 16 + lm;
            float bv = bias[col];
            #pragma unroll
            for (int hh = 0; hh < 2; ++hh) {
                #pragma unroll
                for (int mt = 0; mt < 4; ++mt) {
                    int row = m0 + hh * 128 + wr * 64 + mt * 16 + kg * 4;
                    floatx4 a = acc[hh][mt][hp][nt];
                    #pragma unroll
                    for (int r = 0; r < 4; ++r)
                        out[(size_t)(row + r) * CDIM + col] = a[r] + bv;
                }
            }
        }
    }
}

// ---------------------------------------------------------------------------
// Flash attention (exact round-0 version, verified passing at 83.5 us):
// 256 thr = 4 waves x 64 q-rows; P in registers via K-row permutation on the
// global address side; XOR chunk swizzle for LDS banks; double-buffered async
// K/V staging, one barrier per tile.
// Q,K: [BH][T][64] bf16 (Q pre-scaled); V: [BH][64][T] bf16. Y: [B][T][C] bf16.
// ---------------------------------------------------------------------------
#define BUFSH 8192   // shorts per LDS buffer: K 4096 + V 4096

__device__ __forceinline__ void attn_stage_tile(
    const unsigned short* __restrict__ Kg,
    const unsigned short* __restrict__ Vg,
    size_t base, int kb, unsigned short* buf, int tid)
{
    unsigned short* Kb_ = buf;
    unsigned short* Vb_ = buf + 4096;
    #pragma unroll
    for (int i = 0; i < 2; ++i) {
        int lin = i * 256 + tid;          // 0..511 (16B slots)
        int srow = lin >> 3;              // 0..63
        int chunk = lin & 7;
        int s2 = srow & 31;
        // inverse of the k-permutation: srow2 = mt*16+kg*4+r holds k' = kg*8+mt*4+r
        int grow = (srow & 32) + ((s2 >> 2) & 3) * 8 + ((s2 >> 4) & 1) * 4 + (s2 & 3);
        int gch = chunk ^ (srow & 7);     // XOR swizzle, within-row
        GLOAD16(Kg + base + (size_t)(kb * 64 + grow) * 64 + gch * 8, Kb_ + lin * 8);
        GLOAD16(Vg + base + (size_t)srow * SEQ + kb * 64 + gch * 8, Vb_ + lin * 8);
    }
}

__global__ __launch_bounds__(256) void attn_mfma_kernel(
    const unsigned short* __restrict__ Qg,
    const unsigned short* __restrict__ Kg,
    const unsigned short* __restrict__ Vg,
    unsigned short* __restrict__ Y)
{
    __shared__ __align__(16) unsigned short Smem[2 * BUFSH];   // 32 KB

    const int tid = threadIdx.x, w = tid >> 6, lane = tid & 63;
    const int lm = lane & 15, kg = lane >> 4;
    const int qb = blockIdx.x, bh = blockIdx.y;
    const size_t base = (size_t)bh * SEQ * 64;

    // Q frags in registers: q = qb*256 + w*64 + nt*16 + lm
    short8 qf[4][2];
    #pragma unroll
    for (int nt = 0; nt < 4; ++nt)
        #pragma unroll
        for (int c = 0; c < 2; ++c)
            qf[nt][c] = *(const short8*)(
                Qg + base + (size_t)(qb * 256 + w * 64 + nt * 16 + lm) * 64 + c * 32 + kg * 8);

    const floatx4 zf = {0.f, 0.f, 0.f, 0.f};
    floatx4 O[4][4];     // [q-tile][d-tile]
    #pragma unroll
    for (int nt = 0; nt < 4; ++nt)
        #pragma unroll
        for (int nd = 0; nd < 4; ++nd) O[nt][nd] = zf;
    float lsum[4] = {0.f, 0.f, 0.f, 0.f};

    // prologue: stage tile 0 into buffer 0
    attn_stage_tile(Kg, Vg, base, 0, Smem, tid);

    #pragma unroll 1
    for (int kb = 0; kb < SEQ / 64; ++kb) {
        __syncthreads();   // drains vmcnt(0): buffer kb&1 is ready
        if (kb + 1 < SEQ / 64)
            attn_stage_tile(Kg, Vg, base, kb + 1, Smem + ((kb + 1) & 1) * BUFSH, tid);

        const unsigned short* Ksb = Smem + (kb & 1) * BUFSH;
        const unsigned short* Vsb = Ksb + 4096;
        const int sw = (lm & 7);   // XOR swizzle key for this lane's rows

        // two 32-k chunks; P built entirely in registers
        #pragma unroll
        for (int ch = 0; ch < 2; ++ch) {
            uint4 pa[4];   // PV A-frags (8 bf16 per lane per q-tile)
            #pragma unroll
            for (int mt = 0; mt < 2; ++mt) {
                floatx4 st[4];
                #pragma unroll
                for (int nt = 0; nt < 4; ++nt) st[nt] = zf;
                #pragma unroll
                for (int c = 0; c < 2; ++c) {
                    short8 kf = *(const short8*)(
                        Ksb + (ch * 32 + mt * 16 + lm) * 64 + ((c * 4 + kg) ^ sw) * 8);
                    #pragma unroll
                    for (int nt = 0; nt < 4; ++nt)
                        st[nt] = MFMA_BF16(kf, qf[nt][c], st[nt]);
                }
                #pragma unroll
                for (int nt = 0; nt < 4; ++nt) {
                    float e0 = fast_exp2(st[nt][0]);
                    float e1 = fast_exp2(st[nt][1]);
                    float e2 = fast_exp2(st[nt][2]);
                    float e3 = fast_exp2(st[nt][3]);
                    lsum[nt] += (e0 + e1) + (e2 + e3);
                    if (mt == 0) {
                        pa[nt].x = pack_bf16_trunc(e0, e1);
                        pa[nt].y = pack_bf16_trunc(e2, e3);
                    } else {
                        pa[nt].z = pack_bf16_trunc(e0, e1);
                        pa[nt].w = pack_bf16_trunc(e2, e3);
                    }
                }
            }
            // PV over this 32-k chunk
            #pragma unroll
            for (int nd = 0; nd < 4; ++nd) {
                short8 vb = *(const short8*)(
                    Vsb + (nd * 16 + lm) * 64 + ((ch * 4 + kg) ^ sw) * 8);
                #pragma unroll
                for (int nt = 0; nt < 4; ++nt) {
                    short8 paf;
                    __builtin_memcpy(&paf, &pa[nt], 16);
                    O[nt][nd] = MFMA_BF16(paf, vb, O[nt][nd]);
                }
            }
        }
    }

    // finalize row sums (kg lanes hold disjoint k subsets)
    #pragma unroll
    for (int nt = 0; nt < 4; ++nt) {
        lsum[nt] += __shfl_xor(lsum[nt], 16);
        lsum[nt] += __shfl_xor(lsum[nt], 32);
    }
    float linv[4][4];
    #pragma unroll
    for (int mq = 0; mq < 4; ++mq)
        #pragma unroll
        for (int r = 0; r < 4; ++r)
            linv[mq][r] = 1.0f / __shfl(lsum[mq], kg * 4 + r);

    // epilogue: Y[b][t][h*64 + d] bf16
    const int b = bh >> 4, h = bh & 15;
    #pragma unroll
    for (int mq = 0; mq < 4; ++mq)
        #pragma unroll
        for (int r = 0; r < 4; ++r) {
            int t = qb * 256 + w * 64 + mq * 16 + kg * 4 + r;
            #pragma unroll
            for (int nd = 0; nd < 4; ++nd)
                Y[((size_t)(b * SEQ + t)) * CDIM + h * 64 + nd * 16 + lm] =
                    f2bf(O[mq][nd][r] * linv[mq][r]);
        }
}

extern "C" void kernel_launch(void* const* d_in, const int* in_sizes, int n_in,
                              void* d_out, int out_size, void* d_ws, size_t ws_size,
                              hipStream_t stream) {
    const float* x      = (const float*)d_in[0];
    const float* W_attn = (const float*)d_in[1];
    const float* b_attn = (const float*)d_in[2];
    const float* W_proj = (const float*)d_in[3];
    const float* b_proj = (const float*)d_in[4];
    float* out = (float*)d_out;

    // workspace layout (bf16 buffers)
    char* ws = (char*)d_ws;
    unsigned short* xb  = (unsigned short*)(ws);                      // 16.8 MB
    unsigned short* Wat = (unsigned short*)(ws + (size_t)16777216);   //  6.3 MB
    unsigned short* Wpt = (unsigned short*)(ws + (size_t)23068672);   //  2.1 MB
    unsigned short* Qb  = (unsigned short*)(ws + (size_t)25165824);   // 16.8 MB
    unsigned short* Kb  = (unsigned short*)(ws + (size_t)41943040);   // 16.8 MB
    unsigned short* Vtb = (unsigned short*)(ws + (size_t)58720256);   // 16.8 MB
    unsigned short* Yb  = (unsigned short*)(ws + (size_t)75497472);   // 16.8 MB

    // converts
    conv_bf16_kernel<<<dim3(MROWS * CDIM / 1024), 256, 0, stream>>>(x, xb);
    conv_wt_kernel<<<dim3(3 * CDIM / 64, CDIM / 64), 256, 0, stream>>>(
        W_attn, Wat, CDIM, 3 * CDIM);
    conv_wt_kernel<<<dim3(CDIM / 64, CDIM / 64), 256, 0, stream>>>(
        W_proj, Wpt, CDIM, CDIM);

    // QKV projection: 256x256 8-phase MFMA GEMM (Q pre-scaled for exp2 softmax)
    qkv_mfma_kernel<<<dim3(3 * CDIM / 256, MROWS / 256), 512, 0, stream>>>(
        xb, Wat, b_attn, Qb, Kb, Vtb);

    // attention: 256 q-rows per block, 4 waves x 64 q-rows, dbuf async staging
    attn_mfma_kernel<<<dim3(SEQ / 256, BH), 256, 0, stream>>>(Qb, Kb, Vtb, Yb);

    // output projection: 256x256 8-phase MFMA GEMM
    proj_mfma_kernel<<<dim3(CDIM / 256, MROWS / 256), 512, 0, stream>>>(
        Yb, Wpt, b_proj, out);
}

// Round 5
// 274.931 us; speedup vs baseline: 1.0004x; 1.0004x over previous
//
#include <hip/hip_runtime.h>

#define BATCH 4
#define SEQ   2048
#define CDIM  1024
#define NHEAD 16
#define HDIM  64
#define BH    (BATCH * NHEAD)   // 64
#define MROWS (BATCH * SEQ)     // 8192

typedef __attribute__((ext_vector_type(8))) short  short8;
typedef __attribute__((ext_vector_type(4))) float  floatx4;

#define MFMA_BF16(a, b, c) __builtin_amdgcn_mfma_f32_16x16x32_bf16((a), (b), (c), 0, 0, 0)

// async global->LDS, 16B per lane; LDS dest is wave-uniform base + lane*16
#define GLOAD16(g, l) __builtin_amdgcn_global_load_lds( \
    (__attribute__((address_space(1))) void*)(g),       \
    (__attribute__((address_space(3))) void*)(l), 16, 0, 0)

__device__ __forceinline__ unsigned short f2bf(float f) {
    union { float f; unsigned u; } v; v.f = f;
    unsigned u = v.u;
    return (unsigned short)((u + 0x7FFFu + ((u >> 16) & 1u)) >> 16);
}

__device__ __forceinline__ float fast_exp2(float x) {
#if __has_builtin(__builtin_amdgcn_exp2f)
    return __builtin_amdgcn_exp2f(x);
#else
    return exp2f(x);
#endif
}

// pack two fp32 -> two bf16, truncating (numerator only; denominator fp32)
__device__ __forceinline__ unsigned pack_bf16_trunc(float a, float b) {
    union { float f; unsigned u; } ua, ub;
    ua.f = a; ub.f = b;
    return __builtin_amdgcn_perm(ub.u, ua.u, 0x07060302u);
}

// ---------------------------------------------------------------------------
// fp32 -> bf16 elementwise convert (x). 4 elems/thread.
// ---------------------------------------------------------------------------
__global__ __launch_bounds__(256) void conv_bf16_kernel(
    const float* __restrict__ in, unsigned short* __restrict__ out)
{
    int i = (blockIdx.x * 256 + threadIdx.x) * 4;
    float4 v = *(const float4*)(in + i);
    ushort4 o;
    o.x = f2bf(v.x); o.y = f2bf(v.y); o.z = f2bf(v.z); o.w = f2bf(v.w);
    *(ushort4*)(out + i) = o;
}

// ---------------------------------------------------------------------------
// fp32 [K][N] -> bf16 transposed [N][K] (weights). 64x64 LDS tiles.
// ---------------------------------------------------------------------------
__global__ __launch_bounds__(256) void conv_wt_kernel(
    const float* __restrict__ in, unsigned short* __restrict__ out, int K, int N)
{
    __shared__ float T[64][68];
    const int k0 = blockIdx.y * 64, n0 = blockIdx.x * 64;
    const int tid = threadIdx.x;
    const int r = tid >> 4, c4 = (tid & 15) * 4;
    #pragma unroll
    for (int i = 0; i < 4; ++i) {
        int row = r + i * 16;
        float4 v = *(const float4*)(in + (size_t)(k0 + row) * N + n0 + c4);
        T[row][c4 + 0] = v.x; T[row][c4 + 1] = v.y;
        T[row][c4 + 2] = v.z; T[row][c4 + 3] = v.w;
    }
    __syncthreads();
    #pragma unroll
    for (int i = 0; i < 4; ++i) {
        int nrow = r + i * 16;
        ushort4 o;
        o.x = f2bf(T[c4 + 0][nrow]); o.y = f2bf(T[c4 + 1][nrow]);
        o.z = f2bf(T[c4 + 2][nrow]); o.w = f2bf(T[c4 + 3][nrow]);
        *(ushort4*)(out + (size_t)(n0 + nrow) * K + k0 + c4) = o;
    }
}

// ---------------------------------------------------------------------------
// QKV GEMM: 256x256 tile, BK=64, 512 thr = 8 waves (2M x 4N), 8-phase
// schedule with counted vmcnt (never 0 in main loop), LDS XOR-chunk swizzle
// (applied on the global source side; global_load_lds dest stays linear),
// setprio around each 16-MFMA cluster.  [verified passing: rounds 1,3]
// ---------------------------------------------------------------------------
__global__ __launch_bounds__(512, 2) void qkv_mfma_kernel(
    const unsigned short* __restrict__ A,    // xb [8192][1024]
    const unsigned short* __restrict__ Bt,   // Wat [3072][1024]
    const float* __restrict__ bias,          // [3072]
    unsigned short* __restrict__ Qo,         // [BH][T][64]
    unsigned short* __restrict__ Ko,         // [BH][T][64]
    unsigned short* __restrict__ Vo)         // [BH][64][T]
{
    __shared__ __align__(16) unsigned short L[2 * 32768];   // 128 KB

    const int tid = threadIdx.x;
    const int m0 = blockIdx.y * 256, n0 = blockIdx.x * 256;
    const int w = tid >> 6, lane = tid & 63;
    const int wr = w >> 2, wc = w & 3;        // 2M x 4N
    const int lm = lane & 15, kg = lane >> 4;
    const int sw = lm & 7;                    // read-side XOR swizzle key

    floatx4 acc[2][4][2][2];
    const floatx4 zf = {0.f, 0.f, 0.f, 0.f};
    #pragma unroll
    for (int a = 0; a < 2; ++a)
        #pragma unroll
        for (int b = 0; b < 4; ++b)
            #pragma unroll
            for (int c = 0; c < 2; ++c)
                #pragma unroll
                for (int d = 0; d < 2; ++d) acc[a][b][c][d] = zf;

    short8 af[4][2], bf[2][2];

#define QSTAGE_A(B_, H_, KT_) do {                                            \
    unsigned short* _l = (unsigned short*)L + (B_) * 32768 + (H_) * 8192;     \
    _Pragma("unroll")                                                         \
    for (int _i = 0; _i < 2; ++_i) {                                          \
        int _s = _i * 512 + tid, _r = _s >> 3, _c = _s & 7;                   \
        GLOAD16(A + (size_t)(m0 + (H_) * 128 + _r) * CDIM + (KT_) * 64        \
                   + ((_c ^ (_r & 7)) * 8), _l + _s * 8);                     \
    } } while (0)

#define QSTAGE_B(B_, H_, KT_) do {                                            \
    unsigned short* _l = (unsigned short*)L + (B_) * 32768 + 16384 + (H_) * 8192; \
    _Pragma("unroll")                                                         \
    for (int _i = 0; _i < 2; ++_i) {                                          \
        int _s = _i * 512 + tid, _r = _s >> 3, _c = _s & 7;                   \
        GLOAD16(Bt + (size_t)(n0 + (H_) * 128 + _r) * CDIM + (KT_) * 64       \
                   + ((_c ^ (_r & 7)) * 8), _l + _s * 8);                     \
    } } while (0)

#define QLOAD_A(B_, H_) do {                                                  \
    const unsigned short* _p = (const unsigned short*)L + (B_) * 32768 + (H_) * 8192; \
    _Pragma("unroll")                                                         \
    for (int _m = 0; _m < 4; ++_m) {                                          \
        int _row = wr * 64 + _m * 16 + lm;                                    \
        _Pragma("unroll")                                                     \
        for (int _k = 0; _k < 2; ++_k)                                        \
            af[_m][_k] = *(const short8*)(_p + _row * 64                      \
                          + (((_k * 4 + kg) ^ sw) * 8));                      \
    } } while (0)

#define QLOAD_B(B_, H_) do {                                                  \
    const unsigned short* _p = (const unsigned short*)L + (B_) * 32768 + 16384 + (H_) * 8192; \
    _Pragma("unroll")                                                         \
    for (int _n = 0; _n < 2; ++_n) {                                          \
        int _row = wc * 32 + _n * 16 + lm;                                    \
        _Pragma("unroll")                                                     \
        for (int _k = 0; _k < 2; ++_k)                                        \
            bf[_n][_k] = *(const short8*)(_p + _row * 64                      \
                          + (((_k * 4 + kg) ^ sw) * 8));                      \
    } } while (0)

#define QMFMA(HH_, HP_) do {                                                  \
    _Pragma("unroll") for (int _k = 0; _k < 2; ++_k)                          \
    _Pragma("unroll") for (int _m = 0; _m < 4; ++_m)                          \
    _Pragma("unroll") for (int _n = 0; _n < 2; ++_n)                          \
        acc[HH_][_m][HP_][_n] =                                               \
            MFMA_BF16(af[_m][_k], bf[_n][_k], acc[HH_][_m][HP_][_n]);         \
    } while (0)

#define QPHASE(HH_, HP_, LA_, LB_, STAGE_, VM_) do {                          \
    if (LA_) QLOAD_A(buf, HH_);                                               \
    if (LB_) QLOAD_B(buf, HP_);                                               \
    STAGE_;                                                                   \
    asm volatile("s_waitcnt vmcnt(" #VM_ ")" ::: "memory");                   \
    __builtin_amdgcn_s_barrier();                                             \
    asm volatile("s_waitcnt lgkmcnt(0)" ::: "memory");                        \
    __builtin_amdgcn_sched_barrier(0);                                        \
    __builtin_amdgcn_s_setprio(1);                                            \
    QMFMA(HH_, HP_);                                                          \
    __builtin_amdgcn_s_setprio(0);                                            \
    __builtin_amdgcn_s_barrier();                                             \
    __builtin_amdgcn_sched_barrier(0);                                        \
    } while (0)

    // prologue: tile 0, halves in first-use order; drain to 4 -> A0,B0 landed
    QSTAGE_A(0, 0, 0); QSTAGE_B(0, 0, 0); QSTAGE_B(0, 1, 0); QSTAGE_A(0, 1, 0);
    asm volatile("s_waitcnt vmcnt(4)" ::: "memory");
    __builtin_amdgcn_s_barrier();

    #pragma unroll 1
    for (int t = 0; t < CDIM / 64 - 1; ++t) {
        const int buf = t & 1, nb = buf ^ 1;
        QPHASE(0, 0, 1, 1, QSTAGE_A(nb, 0, t + 1), 4);
        QPHASE(0, 1, 0, 1, QSTAGE_B(nb, 0, t + 1), 4);
        QPHASE(1, 1, 1, 0, QSTAGE_B(nb, 1, t + 1), 4);
        QPHASE(1, 0, 0, 1, QSTAGE_A(nb, 1, t + 1), 4);
    }
    {   // last tile: no staging; drain 2 -> 0
        const int buf = (CDIM / 64 - 1) & 1;
        QPHASE(0, 0, 1, 1, ((void)0), 2);
        QPHASE(0, 1, 0, 1, ((void)0), 0);
        QPHASE(1, 1, 1, 0, ((void)0), 0);
        QPHASE(1, 0, 0, 1, ((void)0), 0);
    }

#undef QPHASE
#undef QMFMA
#undef QLOAD_B
#undef QLOAD_A
#undef QSTAGE_B
#undef QSTAGE_A

    // epilogue: C frag (hh,mt,hp,nt): row = m0+hh*128+wr*64+mt*16+kg*4+r,
    //                                 col = n0+hp*128+wc*32+nt*16+lm
    #pragma unroll
    for (int hp = 0; hp < 2; ++hp) {
        #pragma unroll
        for (int nt = 0; nt < 2; ++nt) {
            int col = n0 + hp * 128 + wc * 32 + nt * 16 + lm;
            float bv = bias[col];
            int which = col >> 10;
            int c1 = col & 1023;
            int h = c1 >> 6, d = c1 & 63;
            #pragma unroll
            for (int hh = 0; hh < 2; ++hh) {
                #pragma unroll
                for (int mt = 0; mt < 4; ++mt) {
                    int m = m0 + hh * 128 + wr * 64 + mt * 16 + kg * 4;
                    int b = m >> 11;
                    int tt = m & 2047;           // tt..tt+3 contiguous
                    int bh = b * NHEAD + h;
                    floatx4 a = acc[hh][mt][hp][nt];
                    if (which == 2) {
                        ushort4 o;
                        o.x = f2bf(a[0] + bv);
                        o.y = f2bf(a[1] + bv);
                        o.z = f2bf(a[2] + bv);
                        o.w = f2bf(a[3] + bv);
                        *(ushort4*)(Vo + ((size_t)bh * 64 + d) * SEQ + tt) = o;
                    } else {
                        unsigned short* dst = (which == 0) ? Qo : Ko;
                        float qs = (which == 0) ? 0.18033688011112042f : 1.0f;
                        #pragma unroll
                        for (int r = 0; r < 4; ++r)
                            dst[((size_t)bh * SEQ + tt + r) * 64 + d] =
                                f2bf((a[r] + bv) * qs);
                    }
                }
            }
        }
    }
}

// ---------------------------------------------------------------------------
// Proj GEMM (reverted to measured-better 128x128 2-phase: 512 blocks, good
// fill; the 256x256 8-phase variant at 128 blocks = 1/CU lost ~5 us).
// ---------------------------------------------------------------------------
#define GBUF (128 * 32)   // shorts per operand buffer

__device__ __forceinline__ void gemm_stage(
    const unsigned short* __restrict__ A, const unsigned short* __restrict__ Bt,
    int K, int m0, int n0, int k0, unsigned short* As, unsigned short* Bs, int tid)
{
    #pragma unroll
    for (int i = 0; i < 2; ++i) {
        int ci = i * 256 + tid;                 // 0..511
        GLOAD16(A  + (size_t)(m0 + (ci >> 2)) * K + k0 + (ci & 3) * 8, As + ci * 8);
        GLOAD16(Bt + (size_t)(n0 + (ci >> 2)) * K + k0 + (ci & 3) * 8, Bs + ci * 8);
    }
}

__global__ __launch_bounds__(256) void proj_mfma_kernel(
    const unsigned short* __restrict__ A,
    const unsigned short* __restrict__ Bt,
    const float* __restrict__ bias,
    float* __restrict__ out)
{
    const int K = CDIM;
    __shared__ __align__(16) unsigned short As2[2 * GBUF];
    __shared__ __align__(16) unsigned short Bs2[2 * GBUF];

    const int tid = threadIdx.x;
    const int m0 = blockIdx.y * 128, n0 = blockIdx.x * 128;
    const int w = tid >> 6, lane = tid & 63;
    const int wm = (w >> 1) * 64, wn = (w & 1) * 64;
    const int lm = lane & 15, kg = lane >> 4;

    floatx4 acc[4][4];
    const floatx4 zf = {0.f, 0.f, 0.f, 0.f};
    #pragma unroll
    for (int mt = 0; mt < 4; ++mt)
        #pragma unroll
        for (int nt = 0; nt < 4; ++nt) acc[mt][nt] = zf;

    gemm_stage(A, Bt, K, m0, n0, 0, As2, Bs2, tid);

    #pragma unroll 1
    for (int kt = 0; kt < K / 32; ++kt) {
        __syncthreads();
        if (kt + 1 < K / 32)
            gemm_stage(A, Bt, K, m0, n0, (kt + 1) * 32,
                       As2 + ((kt + 1) & 1) * GBUF, Bs2 + ((kt + 1) & 1) * GBUF, tid);
        const unsigned short* As = As2 + (kt & 1) * GBUF;
        const unsigned short* Bs = Bs2 + (kt & 1) * GBUF;
        short8 af[4], bfr[4];
        #pragma unroll
        for (int t = 0; t < 4; ++t) {
            af[t]  = *(const short8*)(As + (wm + t * 16 + lm) * 32 + kg * 8);
            bfr[t] = *(const short8*)(Bs + (wn + t * 16 + lm) * 32 + kg * 8);
        }
        #pragma unroll
        for (int mt = 0; mt < 4; ++mt)
            #pragma unroll
            for (int nt = 0; nt < 4; ++nt)
                acc[mt][nt] = MFMA_BF16(af[mt], bfr[nt], acc[mt][nt]);
    }

    #pragma unroll
    for (int nt = 0; nt < 4; ++nt) {
        int col = n0 + wn + nt * 16 + lm;
        float bv = bias[col];
        #pragma unroll
        for (int mt = 0; mt < 4; ++mt) {
            int mbase = m0 + wm + mt * 16 + kg * 4;
            #pragma unroll
            for (int r = 0; r < 4; ++r)
                out[(size_t)(mbase + r) * CDIM + col] = acc[mt][nt][r] + bv;
        }
    }
}

// ---------------------------------------------------------------------------
// Flash attention v9: identical structure/staging/barriers to the verified
// round-0 kernel (256 thr = 4 waves, byte-identical attn_stage_tile); only
// the per-wave q-extent is halved (32 q-rows/wave, 128 q-rows/block) and the
// grid doubled (16 x 64 = 1024 blocks = 4 blocks/CU) so 4 waves/SIMD are
// resident for trans/VALU/MFMA co-issue. Cost: K/V re-read 2x (HBM ~40%).
// Q,K: [BH][T][64] bf16 (Q pre-scaled); V: [BH][64][T] bf16. Y: [B][T][C] bf16.
// ---------------------------------------------------------------------------
#define BUFSH 8192   // shorts per LDS buffer: K 4096 + V 4096

__device__ __forceinline__ void attn_stage_tile(
    const unsigned short* __restrict__ Kg,
    const unsigned short* __restrict__ Vg,
    size_t base, int kb, unsigned short* buf, int tid)
{
    unsigned short* Kb_ = buf;
    unsigned short* Vb_ = buf + 4096;
    #pragma unroll
    for (int i = 0; i < 2; ++i) {
        int lin = i * 256 + tid;          // 0..511 (16B slots)
        int srow = lin >> 3;              // 0..63
        int chunk = lin & 7;
        int s2 = srow & 31;
        // inverse of the k-permutation: srow2 = mt*16+kg*4+r holds k' = kg*8+mt*4+r
        int grow = (srow & 32) + ((s2 >> 2) & 3) * 8 + ((s2 >> 4) & 1) * 4 + (s2 & 3);
        int gch = chunk ^ (srow & 7);     // XOR swizzle, within-row
        GLOAD16(Kg + base + (size_t)(kb * 64 + grow) * 64 + gch * 8, Kb_ + lin * 8);
        GLOAD16(Vg + base + (size_t)srow * SEQ + kb * 64 + gch * 8, Vb_ + lin * 8);
    }
}

__global__ __launch_bounds__(256) void attn_mfma_kernel(
    const unsigned short* __restrict__ Qg,
    const unsigned short* __restrict__ Kg,
    const unsigned short* __restrict__ Vg,
    unsigned short* __restrict__ Y)
{
    __shared__ __align__(16) unsigned short Smem[2 * BUFSH];   // 32 KB

    const int tid = threadIdx.x, w = tid >> 6, lane = tid & 63;
    const int lm = lane & 15, kg = lane >> 4;
    const int qb = blockIdx.x, bh = blockIdx.y;
    const size_t base = (size_t)bh * SEQ * 64;

    // Q frags in registers: q = qb*128 + w*32 + nt*16 + lm
    short8 qf[2][2];
    #pragma unroll
    for (int nt = 0; nt < 2; ++nt)
        #pragma unroll
        for (int c = 0; c < 2; ++c)
            qf[nt][c] = *(const short8*)(
                Qg + base + (size_t)(qb * 128 + w * 32 + nt * 16 + lm) * 64 + c * 32 + kg * 8);

    const floatx4 zf = {0.f, 0.f, 0.f, 0.f};
    floatx4 O[2][4];     // [q-tile][d-tile]
    #pragma unroll
    for (int nt = 0; nt < 2; ++nt)
        #pragma unroll
        for (int nd = 0; nd < 4; ++nd) O[nt][nd] = zf;
    float lsum[2] = {0.f, 0.f};

    // prologue: stage tile 0 into buffer 0
    attn_stage_tile(Kg, Vg, base, 0, Smem, tid);

    #pragma unroll 1
    for (int kb = 0; kb < SEQ / 64; ++kb) {
        __syncthreads();   // drains vmcnt(0): buffer kb&1 is ready
        if (kb + 1 < SEQ / 64)
            attn_stage_tile(Kg, Vg, base, kb + 1, Smem + ((kb + 1) & 1) * BUFSH, tid);

        const unsigned short* Ksb = Smem + (kb & 1) * BUFSH;
        const unsigned short* Vsb = Ksb + 4096;
        const int sw = (lm & 7);   // XOR swizzle key for this lane's rows

        // two 32-k chunks; P built entirely in registers
        #pragma unroll
        for (int ch = 0; ch < 2; ++ch) {
            uint4 pa[2];   // PV A-frags (8 bf16 per lane per q-tile)
            #pragma unroll
            for (int mt = 0; mt < 2; ++mt) {
                floatx4 st[2];
                #pragma unroll
                for (int nt = 0; nt < 2; ++nt) st[nt] = zf;
                #pragma unroll
                for (int c = 0; c < 2; ++c) {
                    short8 kf = *(const short8*)(
                        Ksb + (ch * 32 + mt * 16 + lm) * 64 + ((c * 4 + kg) ^ sw) * 8);
                    #pragma unroll
                    for (int nt = 0; nt < 2; ++nt)
                        st[nt] = MFMA_BF16(kf, qf[nt][c], st[nt]);
                }
                #pragma unroll
                for (int nt = 0; nt < 2; ++nt) {
                    float e0 = fast_exp2(st[nt][0]);
                    float e1 = fast_exp2(st[nt][1]);
                    float e2 = fast_exp2(st[nt][2]);
                    float e3 = fast_exp2(st[nt][3]);
                    lsum[nt] += (e0 + e1) + (e2 + e3);
                    if (mt == 0) {
                        pa[nt].x = pack_bf16_trunc(e0, e1);
                        pa[nt].y = pack_bf16_trunc(e2, e3);
                    } else {
                        pa[nt].z = pack_bf16_trunc(e0, e1);
                        pa[nt].w = pack_bf16_trunc(e2, e3);
                    }
                }
            }
            // PV over this 32-k chunk
            #pragma unroll
            for (int nd = 0; nd < 4; ++nd) {
                short8 vb = *(const short8*)(
                    Vsb + (nd * 16 + lm) * 64 + ((ch * 4 + kg) ^ sw) * 8);
                #pragma unroll
                for (int nt = 0; nt < 2; ++nt) {
                    short8 paf;
                    __builtin_memcpy(&paf, &pa[nt], 16);
                    O[nt][nd] = MFMA_BF16(paf, vb, O[nt][nd]);
                }
            }
        }
    }

    // finalize row sums (kg lanes hold disjoint k subsets)
    #pragma unroll
    for (int nt = 0; nt < 2; ++nt) {
        lsum[nt] += __shfl_xor(lsum[nt], 16);
        lsum[nt] += __shfl_xor(lsum[nt], 32);
    }
    float linv[2][4];
    #pragma unroll
    for (int mq = 0; mq < 2; ++mq)
        #pragma unroll
        for (int r = 0; r < 4; ++r)
            linv[mq][r] = 1.0f / __shfl(lsum[mq], kg * 4 + r);

    // epilogue: Y[b][t][h*64 + d] bf16
    const int b = bh >> 4, h = bh & 15;
    #pragma unroll
    for (int mq = 0; mq < 2; ++mq)
        #pragma unroll
        for (int r = 0; r < 4; ++r) {
            int t = qb * 128 + w * 32 + mq * 16 + kg * 4 + r;
            #pragma unroll
            for (int nd = 0; nd < 4; ++nd)
                Y[((size_t)(b * SEQ + t)) * CDIM + h * 64 + nd * 16 + lm] =
                    f2bf(O[mq][nd][r] * linv[mq][r]);
        }
}

extern "C" void kernel_launch(void* const* d_in, const int* in_sizes, int n_in,
                              void* d_out, int out_size, void* d_ws, size_t ws_size,
                              hipStream_t stream) {
    const float* x      = (const float*)d_in[0];
    const float* W_attn = (const float*)d_in[1];
    const float* b_attn = (const float*)d_in[2];
    const float* W_proj = (const float*)d_in[3];
    const float* b_proj = (const float*)d_in[4];
    float* out = (float*)d_out;

    // workspace layout (bf16 buffers)
    char* ws = (char*)d_ws;
    unsigned short* xb  = (unsigned short*)(ws);                      // 16.8 MB
    unsigned short* Wat = (unsigned short*)(ws + (size_t)16777216);   //  6.3 MB
    unsigned short* Wpt = (unsigned short*)(ws + (size_t)23068672);   //  2.1 MB
    unsigned short* Qb  = (unsigned short*)(ws + (size_t)25165824);   // 16.8 MB
    unsigned short* Kb  = (unsigned short*)(ws + (size_t)41943040);   // 16.8 MB
    unsigned short* Vtb = (unsigned short*)(ws + (size_t)58720256);   // 16.8 MB
    unsigned short* Yb  = (unsigned short*)(ws + (size_t)75497472);   // 16.8 MB

    // converts
    conv_bf16_kernel<<<dim3(MROWS * CDIM / 1024), 256, 0, stream>>>(x, xb);
    conv_wt_kernel<<<dim3(3 * CDIM / 64, CDIM / 64), 256, 0, stream>>>(
        W_attn, Wat, CDIM, 3 * CDIM);
    conv_wt_kernel<<<dim3(CDIM / 64, CDIM / 64), 256, 0, stream>>>(
        W_proj, Wpt, CDIM, CDIM);

    // QKV projection: 256x256 8-phase MFMA GEMM (Q pre-scaled for exp2 softmax)
    qkv_mfma_kernel<<<dim3(3 * CDIM / 256, MROWS / 256), 512, 0, stream>>>(
        xb, Wat, b_attn, Qb, Kb, Vtb);

    // attention: 128 q-rows per block, 4 waves x 32 q-rows, dbuf async staging
    attn_mfma_kernel<<<dim3(SEQ / 128, BH), 256, 0, stream>>>(Qb, Kb, Vtb, Yb);

    // output projection: 128x128 2-phase MFMA GEMM (512 blocks, good fill)
    proj_mfma_kernel<<<dim3(CDIM / 128, MROWS / 128), 256, 0, stream>>>(
        Yb, Wpt, b_proj, out);
}

// Round 7
// 273.113 us; speedup vs baseline: 1.0071x; 1.0067x over previous
//
#include <hip/hip_runtime.h>

#define BATCH 4
#define SEQ   2048
#define CDIM  1024
#define NHEAD 16
#define HDIM  64
#define BH    (BATCH * NHEAD)   // 64
#define MROWS (BATCH * SEQ)     // 8192

typedef __attribute__((ext_vector_type(8))) short  short8;
typedef __attribute__((ext_vector_type(4))) float  floatx4;

#define MFMA_BF16(a, b, c) __builtin_amdgcn_mfma_f32_16x16x32_bf16((a), (b), (c), 0, 0, 0)

// async global->LDS, 16B per lane; LDS dest is wave-uniform base + lane*16
#define GLOAD16(g, l) __builtin_amdgcn_global_load_lds( \
    (__attribute__((address_space(1))) void*)(g),       \
    (__attribute__((address_space(3))) void*)(l), 16, 0, 0)

__device__ __forceinline__ unsigned short f2bf(float f) {
    union { float f; unsigned u; } v; v.f = f;
    unsigned u = v.u;
    return (unsigned short)((u + 0x7FFFu + ((u >> 16) & 1u)) >> 16);
}

__device__ __forceinline__ float fast_exp2(float x) {
#if __has_builtin(__builtin_amdgcn_exp2f)
    return __builtin_amdgcn_exp2f(x);
#else
    return exp2f(x);
#endif
}

// pack two fp32 -> two bf16, truncating (numerator only; denominator fp32)
__device__ __forceinline__ unsigned pack_bf16_trunc(float a, float b) {
    union { float f; unsigned u; } ua, ub;
    ua.f = a; ub.f = b;
    return __builtin_amdgcn_perm(ub.u, ua.u, 0x07060302u);
}

// ---------------------------------------------------------------------------
// Merged converts (one launch instead of three):
//  blocks [0, 8192):        x fp32 -> bf16, 4 elems/thread
//  blocks [8192, 8960):     W_attn fp32 [K][N] -> bf16 [N][K] (64x64 tiles)
//  blocks [8960, 9216):     W_proj  same
// ---------------------------------------------------------------------------
__global__ __launch_bounds__(256) void conv_all_kernel(
    const float* __restrict__ x,  unsigned short* __restrict__ xb,
    const float* __restrict__ Wa, unsigned short* __restrict__ Wat,
    const float* __restrict__ Wp, unsigned short* __restrict__ Wpt)
{
    const int bx = blockIdx.x, tid = threadIdx.x;
    if (bx < 8192) {
        int i = (bx * 256 + tid) * 4;
        float4 v = *(const float4*)(x + i);
        ushort4 o;
        o.x = f2bf(v.x); o.y = f2bf(v.y); o.z = f2bf(v.z); o.w = f2bf(v.w);
        *(ushort4*)(xb + i) = o;
        return;
    }
    __shared__ float T[64][68];
    const float* in; unsigned short* out; int N, k0, n0;
    if (bx < 8192 + 768) {
        int t = bx - 8192;
        in = Wa; out = Wat; N = 3 * CDIM;
        n0 = (t % 48) * 64; k0 = (t / 48) * 64;
    } else {
        int t = bx - 8960;
        in = Wp; out = Wpt; N = CDIM;
        n0 = (t & 15) * 64; k0 = (t >> 4) * 64;
    }
    const int K = CDIM;
    const int r = tid >> 4, c4 = (tid & 15) * 4;
    #pragma unroll
    for (int i = 0; i < 4; ++i) {
        int row = r + i * 16;
        float4 v = *(const float4*)(in + (size_t)(k0 + row) * N + n0 + c4);
        T[row][c4 + 0] = v.x; T[row][c4 + 1] = v.y;
        T[row][c4 + 2] = v.z; T[row][c4 + 3] = v.w;
    }
    __syncthreads();
    #pragma unroll
    for (int i = 0; i < 4; ++i) {
        int nrow = r + i * 16;
        ushort4 o;
        o.x = f2bf(T[c4 + 0][nrow]); o.y = f2bf(T[c4 + 1][nrow]);
        o.z = f2bf(T[c4 + 2][nrow]); o.w = f2bf(T[c4 + 3][nrow]);
        *(ushort4*)(out + (size_t)(n0 + nrow) * K + k0 + c4) = o;
    }
}

// ---------------------------------------------------------------------------
// QKV GEMM: 256x256 tile, BK=64, 512 thr = 8 waves (2M x 4N), 8-phase
// schedule with counted vmcnt (symmetric stage: 2 loads/thread per half;
// waits 4,4,4,4 - race-screened in rounds 1/3/4), LDS XOR-chunk swizzle
// (global-source side), setprio around each 16-MFMA cluster.
// Grid: 384 blocks 1D with XCD-aware bijective swizzle (384 % 8 == 0).
// ---------------------------------------------------------------------------
__global__ __launch_bounds__(512, 2) void qkv_mfma_kernel(
    const unsigned short* __restrict__ A,    // xb [8192][1024]
    const unsigned short* __restrict__ Bt,   // Wat [3072][1024]
    const float* __restrict__ bias,          // [3072]
    unsigned short* __restrict__ Qo,         // [BH][T][64]
    unsigned short* __restrict__ Ko,         // [BH][T][64]
    unsigned short* __restrict__ Vo)         // [BH][64][T]
{
    __shared__ __align__(16) unsigned short L[2 * 32768];   // 128 KB

    const int tid = threadIdx.x;
    // XCD swizzle: XCD c owns flat%8==c; its blocks walk tiles contiguously.
    const int flat = blockIdx.x;
    const int swz = (flat & 7) * 48 + (flat >> 3);
    const int m0 = (swz / 12) * 256, n0 = (swz % 12) * 256;
    const int w = tid >> 6, lane = tid & 63;
    const int wr = w >> 2, wc = w & 3;        // 2M x 4N
    const int lm = lane & 15, kg = lane >> 4;
    const int sw = lm & 7;                    // read-side XOR swizzle key

    floatx4 acc[2][4][2][2];
    const floatx4 zf = {0.f, 0.f, 0.f, 0.f};
    #pragma unroll
    for (int a = 0; a < 2; ++a)
        #pragma unroll
        for (int b = 0; b < 4; ++b)
            #pragma unroll
            for (int c = 0; c < 2; ++c)
                #pragma unroll
                for (int d = 0; d < 2; ++d) acc[a][b][c][d] = zf;

    short8 af[4][2], bf[2][2];

#define QSTAGE_A(B_, H_, KT_) do {                                            \
    unsigned short* _l = (unsigned short*)L + (B_) * 32768 + (H_) * 8192;     \
    _Pragma("unroll")                                                         \
    for (int _i = 0; _i < 2; ++_i) {                                          \
        int _s = _i * 512 + tid, _r = _s >> 3, _c = _s & 7;                   \
        GLOAD16(A + (size_t)(m0 + (H_) * 128 + _r) * CDIM + (KT_) * 64        \
                   + ((_c ^ (_r & 7)) * 8), _l + _s * 8);                     \
    } } while (0)

#define QSTAGE_B(B_, H_, KT_) do {                                            \
    unsigned short* _l = (unsigned short*)L + (B_) * 32768 + 16384 + (H_) * 8192; \
    _Pragma("unroll")                                                         \
    for (int _i = 0; _i < 2; ++_i) {                                          \
        int _s = _i * 512 + tid, _r = _s >> 3, _c = _s & 7;                   \
        GLOAD16(Bt + (size_t)(n0 + (H_) * 128 + _r) * CDIM + (KT_) * 64       \
                   + ((_c ^ (_r & 7)) * 8), _l + _s * 8);                     \
    } } while (0)

#define QLOAD_A(B_, H_) do {                                                  \
    const unsigned short* _p = (const unsigned short*)L + (B_) * 32768 + (H_) * 8192; \
    _Pragma("unroll")                                                         \
    for (int _m = 0; _m < 4; ++_m) {                                          \
        int _row = wr * 64 + _m * 16 + lm;                                    \
        _Pragma("unroll")                                                     \
        for (int _k = 0; _k < 2; ++_k)                                        \
            af[_m][_k] = *(const short8*)(_p + _row * 64                      \
                          + (((_k * 4 + kg) ^ sw) * 8));                      \
    } } while (0)

#define QLOAD_B(B_, H_) do {                                                  \
    const unsigned short* _p = (const unsigned short*)L + (B_) * 32768 + 16384 + (H_) * 8192; \
    _Pragma("unroll")                                                         \
    for (int _n = 0; _n < 2; ++_n) {                                          \
        int _row = wc * 32 + _n * 16 + lm;                                    \
        _Pragma("unroll")                                                     \
        for (int _k = 0; _k < 2; ++_k)                                        \
            bf[_n][_k] = *(const short8*)(_p + _row * 64                      \
                          + (((_k * 4 + kg) ^ sw) * 8));                      \
    } } while (0)

#define QMFMA(HH_, HP_) do {                                                  \
    _Pragma("unroll") for (int _k = 0; _k < 2; ++_k)                          \
    _Pragma("unroll") for (int _m = 0; _m < 4; ++_m)                          \
    _Pragma("unroll") for (int _n = 0; _n < 2; ++_n)                          \
        acc[HH_][_m][HP_][_n] =                                               \
            MFMA_BF16(af[_m][_k], bf[_n][_k], acc[HH_][_m][HP_][_n]);         \
    } while (0)

#define QPHASE(HH_, HP_, LA_, LB_, STAGE_, VM_) do {                          \
    if (LA_) QLOAD_A(buf, HH_);                                               \
    if (LB_) QLOAD_B(buf, HP_);                                               \
    STAGE_;                                                                   \
    asm volatile("s_waitcnt vmcnt(" #VM_ ")" ::: "memory");                   \
    __builtin_amdgcn_s_barrier();                                             \
    asm volatile("s_waitcnt lgkmcnt(0)" ::: "memory");                        \
    __builtin_amdgcn_sched_barrier(0);                                        \
    __builtin_amdgcn_s_setprio(1);                                            \
    QMFMA(HH_, HP_);                                                          \
    __builtin_amdgcn_s_setprio(0);                                            \
    __builtin_amdgcn_s_barrier();                                             \
    __builtin_amdgcn_sched_barrier(0);                                        \
    } while (0)

    // prologue: tile 0, halves in first-use order; drain to 4 -> A0,B0 landed
    QSTAGE_A(0, 0, 0); QSTAGE_B(0, 0, 0); QSTAGE_B(0, 1, 0); QSTAGE_A(0, 1, 0);
    asm volatile("s_waitcnt vmcnt(4)" ::: "memory");
    __builtin_amdgcn_s_barrier();

    #pragma unroll 1
    for (int t = 0; t < CDIM / 64 - 1; ++t) {
        const int buf = t & 1, nb = buf ^ 1;
        QPHASE(0, 0, 1, 1, QSTAGE_A(nb, 0, t + 1), 4);
        QPHASE(0, 1, 0, 1, QSTAGE_B(nb, 0, t + 1), 4);
        QPHASE(1, 1, 1, 0, QSTAGE_B(nb, 1, t + 1), 4);
        QPHASE(1, 0, 0, 1, QSTAGE_A(nb, 1, t + 1), 4);
    }
    {   // last tile: no staging; drain 2 -> 0
        const int buf = (CDIM / 64 - 1) & 1;
        QPHASE(0, 0, 1, 1, ((void)0), 2);
        QPHASE(0, 1, 0, 1, ((void)0), 0);
        QPHASE(1, 1, 1, 0, ((void)0), 0);
        QPHASE(1, 0, 0, 1, ((void)0), 0);
    }

#undef QPHASE
#undef QMFMA
#undef QLOAD_B
#undef QLOAD_A
#undef QSTAGE_B
#undef QSTAGE_A

    // epilogue: C frag (hh,mt,hp,nt): row = m0+hh*128+wr*64+mt*16+kg*4+r,
    //                                 col = n0+hp*128+wc*32+nt*16+lm
    #pragma unroll
    for (int hp = 0; hp < 2; ++hp) {
        #pragma unroll
        for (int nt = 0; nt < 2; ++nt) {
            int col = n0 + hp * 128 + wc * 32 + nt * 16 + lm;
            float bv = bias[col];
            int which = col >> 10;
            int c1 = col & 1023;
            int h = c1 >> 6, d = c1 & 63;
            #pragma unroll
            for (int hh = 0; hh < 2; ++hh) {
                #pragma unroll
                for (int mt = 0; mt < 4; ++mt) {
                    int m = m0 + hh * 128 + wr * 64 + mt * 16 + kg * 4;
                    int b = m >> 11;
                    int tt = m & 2047;           // tt..tt+3 contiguous
                    int bh = b * NHEAD + h;
                    floatx4 a = acc[hh][mt][hp][nt];
                    if (which == 2) {
                        ushort4 o;
                        o.x = f2bf(a[0] + bv);
                        o.y = f2bf(a[1] + bv);
                        o.z = f2bf(a[2] + bv);
                        o.w = f2bf(a[3] + bv);
                        *(ushort4*)(Vo + ((size_t)bh * 64 + d) * SEQ + tt) = o;
                    } else {
                        unsigned short* dst = (which == 0) ? Qo : Ko;
                        float qs = (which == 0) ? 0.18033688011112042f : 1.0f;
                        #pragma unroll
                        for (int r = 0; r < 4; ++r)
                            dst[((size_t)bh * SEQ + tt + r) * 64 + d] =
                                f2bf((a[r] + bv) * qs);
                    }
                }
            }
        }
    }
}

// ---------------------------------------------------------------------------
// Proj GEMM: proven 128x128 2-phase (512 blocks, good fill).
// ---------------------------------------------------------------------------
#define GBUF (128 * 32)   // shorts per operand buffer

__device__ __forceinline__ void gemm_stage(
    const unsigned short* __restrict__ A, const unsigned short* __restrict__ Bt,
    int K, int m0, int n0, int k0, unsigned short* As, unsigned short* Bs, int tid)
{
    #pragma unroll
    for (int i = 0; i < 2; ++i) {
        int ci = i * 256 + tid;                 // 0..511
        GLOAD16(A  + (size_t)(m0 + (ci >> 2)) * K + k0 + (ci & 3) * 8, As + ci * 8);
        GLOAD16(Bt + (size_t)(n0 + (ci >> 2)) * K + k0 + (ci & 3) * 8, Bs + ci * 8);
    }
}

__global__ __launch_bounds__(256) void proj_mfma_kernel(
    const unsigned short* __restrict__ A,
    const unsigned short* __restrict__ Bt,
    const float* __restrict__ bias,
    float* __restrict__ out)
{
    const int K = CDIM;
    __shared__ __align__(16) unsigned short As2[2 * GBUF];
    __shared__ __align__(16) unsigned short Bs2[2 * GBUF];

    const int tid = threadIdx.x;
    const int m0 = blockIdx.y * 128, n0 = blockIdx.x * 128;
    const int w = tid >> 6, lane = tid & 63;
    const int wm = (w >> 1) * 64, wn = (w & 1) * 64;
    const int lm = lane & 15, kg = lane >> 4;

    floatx4 acc[4][4];
    const floatx4 zf = {0.f, 0.f, 0.f, 0.f};
    #pragma unroll
    for (int mt = 0; mt < 4; ++mt)
        #pragma unroll
        for (int nt = 0; nt < 4; ++nt) acc[mt][nt] = zf;

    gemm_stage(A, Bt, K, m0, n0, 0, As2, Bs2, tid);

    #pragma unroll 1
    for (int kt = 0; kt < K / 32; ++kt) {
        __syncthreads();
        if (kt + 1 < K / 32)
            gemm_stage(A, Bt, K, m0, n0, (kt + 1) * 32,
                       As2 + ((kt + 1) & 1) * GBUF, Bs2 + ((kt + 1) & 1) * GBUF, tid);
        const unsigned short* As = As2 + (kt & 1) * GBUF;
        const unsigned short* Bs = Bs2 + (kt & 1) * GBUF;
        short8 af[4], bfr[4];
        #pragma unroll
        for (int t = 0; t < 4; ++t) {
            af[t]  = *(const short8*)(As + (wm + t * 16 + lm) * 32 + kg * 8);
            bfr[t] = *(const short8*)(Bs + (wn + t * 16 + lm) * 32 + kg * 8);
        }
        #pragma unroll
        for (int mt = 0; mt < 4; ++mt)
            #pragma unroll
            for (int nt = 0; nt < 4; ++nt)
                acc[mt][nt] = MFMA_BF16(af[mt], bfr[nt], acc[mt][nt]);
    }

    #pragma unroll
    for (int nt = 0; nt < 4; ++nt) {
        int col = n0 + wn + nt * 16 + lm;
        float bv = bias[col];
        #pragma unroll
        for (int mt = 0; mt < 4; ++mt) {
            int mbase = m0 + wm + mt * 16 + kg * 4;
            #pragma unroll
            for (int r = 0; r < 4; ++r)
                out[(size_t)(mbase + r) * CDIM + col] = acc[mt][nt][r] + bv;
        }
    }
}

// ---------------------------------------------------------------------------
// Flash attention (round-4 version, verified 81.3 us, passed replay):
// 256 thr = 4 waves x 32 q-rows, 128 q-rows/block, grid 16x64; P in
// registers via K-row permutation on the global address side; XOR chunk
// swizzle; dbuf async staging, one barrier per tile.
// Q,K: [BH][T][64] bf16 (Q pre-scaled); V: [BH][64][T] bf16. Y: [B][T][C] bf16.
// ---------------------------------------------------------------------------
#define BUFSH 8192   // shorts per LDS buffer: K 4096 + V 4096

__device__ __forceinline__ void attn_stage_tile(
    const unsigned short* __restrict__ Kg,
    const unsigned short* __restrict__ Vg,
    size_t base, int kb, unsigned short* buf, int tid)
{
    unsigned short* Kb_ = buf;
    unsigned short* Vb_ = buf + 4096;
    #pragma unroll
    for (int i = 0; i < 2; ++i) {
        int lin = i * 256 + tid;          // 0..511 (16B slots)
        int srow = lin >> 3;              // 0..63
        int chunk = lin & 7;
        int s2 = srow & 31;
        // inverse of the k-permutation: srow2 = mt*16+kg*4+r holds k' = kg*8+mt*4+r
        int grow = (srow & 32) + ((s2 >> 2) & 3) * 8 + ((s2 >> 4) & 1) * 4 + (s2 & 3);
        int gch = chunk ^ (srow & 7);     // XOR swizzle, within-row
        GLOAD16(Kg + base + (size_t)(kb * 64 + grow) * 64 + gch * 8, Kb_ + lin * 8);
        GLOAD16(Vg + base + (size_t)srow * SEQ + kb * 64 + gch * 8, Vb_ + lin * 8);
    }
}

__global__ __launch_bounds__(256) void attn_mfma_kernel(
    const unsigned short* __restrict__ Qg,
    const unsigned short* __restrict__ Kg,
    const unsigned short* __restrict__ Vg,
    unsigned short* __restrict__ Y)
{
    __shared__ __align__(16) unsigned short Smem[2 * BUFSH];   // 32 KB

    const int tid = threadIdx.x, w = tid >> 6, lane = tid & 63;
    const int lm = lane & 15, kg = lane >> 4;
    const int qb = blockIdx.x, bh = blockIdx.y;
    const size_t base = (size_t)bh * SEQ * 64;

    // Q frags in registers: q = qb*128 + w*32 + nt*16 + lm
    short8 qf[2][2];
    #pragma unroll
    for (int nt = 0; nt < 2; ++nt)
        #pragma unroll
        for (int c = 0; c < 2; ++c)
            qf[nt][c] = *(const short8*)(
                Qg + base + (size_t)(qb * 128 + w * 32 + nt * 16 + lm) * 64 + c * 32 + kg * 8);

    const floatx4 zf = {0.f, 0.f, 0.f, 0.f};
    floatx4 O[2][4];     // [q-tile][d-tile]
    #pragma unroll
    for (int nt = 0; nt < 2; ++nt)
        #pragma unroll
        for (int nd = 0; nd < 4; ++nd) O[nt][nd] = zf;
    float lsum[2] = {0.f, 0.f};

    // prologue: stage tile 0 into buffer 0
    attn_stage_tile(Kg, Vg, base, 0, Smem, tid);

    #pragma unroll 1
    for (int kb = 0; kb < SEQ / 64; ++kb) {
        __syncthreads();   // drains vmcnt(0): buffer kb&1 is ready
        if (kb + 1 < SEQ / 64)
            attn_stage_tile(Kg, Vg, base, kb + 1, Smem + ((kb + 1) & 1) * BUFSH, tid);

        const unsigned short* Ksb = Smem + (kb & 1) * BUFSH;
        const unsigned short* Vsb = Ksb + 4096;
        const int sw = (lm & 7);   // XOR swizzle key for this lane's rows

        // two 32-k chunks; P built entirely in registers
        #pragma unroll
        for (int ch = 0; ch < 2; ++ch) {
            uint4 pa[2];   // PV A-frags (8 bf16 per lane per q-tile)
            #pragma unroll
            for (int mt = 0; mt < 2; ++mt) {
                floatx4 st[2];
                #pragma unroll
                for (int nt = 0; nt < 2; ++nt) st[nt] = zf;
                #pragma unroll
                for (int c = 0; c < 2; ++c) {
                    short8 kf = *(const short8*)(
                        Ksb + (ch * 32 + mt * 16 + lm) * 64 + ((c * 4 + kg) ^ sw) * 8);
                    #pragma unroll
                    for (int nt = 0; nt < 2; ++nt)
                        st[nt] = MFMA_BF16(kf, qf[nt][c], st[nt]);
                }
                #pragma unroll
                for (int nt = 0; nt < 2; ++nt) {
                    float e0 = fast_exp2(st[nt][0]);
                    float e1 = fast_exp2(st[nt][1]);
                    float e2 = fast_exp2(st[nt][2]);
                    float e3 = fast_exp2(st[nt][3]);
                    lsum[nt] += (e0 + e1) + (e2 + e3);
                    if (mt == 0) {
                        pa[nt].x = pack_bf16_trunc(e0, e1);
                        pa[nt].y = pack_bf16_trunc(e2, e3);
                    } else {
                        pa[nt].z = pack_bf16_trunc(e0, e1);
                        pa[nt].w = pack_bf16_trunc(e2, e3);
                    }
                }
            }
            // PV over this 32-k chunk
            #pragma unroll
            for (int nd = 0; nd < 4; ++nd) {
                short8 vb = *(const short8*)(
                    Vsb + (nd * 16 + lm) * 64 + ((ch * 4 + kg) ^ sw) * 8);
                #pragma unroll
                for (int nt = 0; nt < 2; ++nt) {
                    short8 paf;
                    __builtin_memcpy(&paf, &pa[nt], 16);
                    O[nt][nd] = MFMA_BF16(paf, vb, O[nt][nd]);
                }
            }
        }
    }

    // finalize row sums (kg lanes hold disjoint k subsets)
    #pragma unroll
    for (int nt = 0; nt < 2; ++nt) {
        lsum[nt] += __shfl_xor(lsum[nt], 16);
        lsum[nt] += __shfl_xor(lsum[nt], 32);
    }
    float linv[2][4];
    #pragma unroll
    for (int mq = 0; mq < 2; ++mq)
        #pragma unroll
        for (int r = 0; r < 4; ++r)
            linv[mq][r] = 1.0f / __shfl(lsum[mq], kg * 4 + r);

    // epilogue: Y[b][t][h*64 + d] bf16
    const int b = bh >> 4, h = bh & 15;
    #pragma unroll
    for (int mq = 0; mq < 2; ++mq)
        #pragma unroll
        for (int r = 0; r < 4; ++r) {
            int t = qb * 128 + w * 32 + mq * 16 + kg * 4 + r;
            #pragma unroll
            for (int nd = 0; nd < 4; ++nd)
                Y[((size_t)(b * SEQ + t)) * CDIM + h * 64 + nd * 16 + lm] =
                    f2bf(O[mq][nd][r] * linv[mq][r]);
        }
}

extern "C" void kernel_launch(void* const* d_in, const int* in_sizes, int n_in,
                              void* d_out, int out_size, void* d_ws, size_t ws_size,
                              hipStream_t stream) {
    const float* x      = (const float*)d_in[0];
    const float* W_attn = (const float*)d_in[1];
    const float* b_attn = (const float*)d_in[2];
    const float* W_proj = (const float*)d_in[3];
    const float* b_proj = (const float*)d_in[4];
    float* out = (float*)d_out;

    // workspace layout (bf16 buffers)
    char* ws = (char*)d_ws;
    unsigned short* xb  = (unsigned short*)(ws);                      // 16.8 MB
    unsigned short* Wat = (unsigned short*)(ws + (size_t)16777216);   //  6.3 MB
    unsigned short* Wpt = (unsigned short*)(ws + (size_t)23068672);   //  2.1 MB
    unsigned short* Qb  = (unsigned short*)(ws + (size_t)25165824);   // 16.8 MB
    unsigned short* Kb  = (unsigned short*)(ws + (size_t)41943040);   // 16.8 MB
    unsigned short* Vtb = (unsigned short*)(ws + (size_t)58720256);   // 16.8 MB
    unsigned short* Yb  = (unsigned short*)(ws + (size_t)75497472);   // 16.8 MB

    // all converts in one launch: 8192 (x) + 768 (W_attn) + 256 (W_proj)
    conv_all_kernel<<<dim3(9216), 256, 0, stream>>>(
        x, xb, W_attn, Wat, W_proj, Wpt);

    // QKV projection: 256x256 8-phase, 384 blocks, XCD-swizzled 1D grid
    qkv_mfma_kernel<<<dim3(384), 512, 0, stream>>>(
        xb, Wat, b_attn, Qb, Kb, Vtb);

    // attention: 128 q-rows per block, 4 waves x 32 q-rows, dbuf async staging
    attn_mfma_kernel<<<dim3(SEQ / 128, BH), 256, 0, stream>>>(Qb, Kb, Vtb, Yb);

    // output projection: 128x128 2-phase MFMA GEMM (512 blocks, good fill)
    proj_mfma_kernel<<<dim3(CDIM / 128, MROWS / 128), 256, 0, stream>>>(
        Yb, Wpt, b_proj, out);
}

// Round 9
// 265.727 us; speedup vs baseline: 1.0351x; 1.0278x over previous
//
#include <hip/hip_runtime.h>

#define BATCH 4
#define SEQ   2048
#define CDIM  1024
#define NHEAD 16
#define HDIM  64
#define BH    (BATCH * NHEAD)   // 64
#define MROWS (BATCH * SEQ)     // 8192

typedef __attribute__((ext_vector_type(8))) short  short8;
typedef __attribute__((ext_vector_type(4))) float  floatx4;

#define MFMA_BF16(a, b, c) __builtin_amdgcn_mfma_f32_16x16x32_bf16((a), (b), (c), 0, 0, 0)

// async global->LDS, 16B per lane; LDS dest is wave-uniform base + lane*16
#define GLOAD16(g, l) __builtin_amdgcn_global_load_lds( \
    (__attribute__((address_space(1))) void*)(g),       \
    (__attribute__((address_space(3))) void*)(l), 16, 0, 0)

__device__ __forceinline__ unsigned short f2bf(float f) {
    union { float f; unsigned u; } v; v.f = f;
    unsigned u = v.u;
    return (unsigned short)((u + 0x7FFFu + ((u >> 16) & 1u)) >> 16);
}

__device__ __forceinline__ float fast_exp2(float x) {
#if __has_builtin(__builtin_amdgcn_exp2f)
    return __builtin_amdgcn_exp2f(x);
#else
    return exp2f(x);
#endif
}

// pack two fp32 -> two bf16, truncating (numerator only; denominator fp32)
__device__ __forceinline__ unsigned pack_bf16_trunc(float a, float b) {
    union { float f; unsigned u; } ua, ub;
    ua.f = a; ub.f = b;
    return __builtin_amdgcn_perm(ub.u, ua.u, 0x07060302u);
}

// ---------------------------------------------------------------------------
// Merged converts (one launch instead of three):
//  blocks [0, 8192):        x fp32 -> bf16, 4 elems/thread
//  blocks [8192, 8960):     W_attn fp32 [K][N] -> bf16 [N][K] (64x64 tiles)
//  blocks [8960, 9216):     W_proj  same
// ---------------------------------------------------------------------------
__global__ __launch_bounds__(256) void conv_all_kernel(
    const float* __restrict__ x,  unsigned short* __restrict__ xb,
    const float* __restrict__ Wa, unsigned short* __restrict__ Wat,
    const float* __restrict__ Wp, unsigned short* __restrict__ Wpt)
{
    const int bx = blockIdx.x, tid = threadIdx.x;
    if (bx < 8192) {
        int i = (bx * 256 + tid) * 4;
        float4 v = *(const float4*)(x + i);
        ushort4 o;
        o.x = f2bf(v.x); o.y = f2bf(v.y); o.z = f2bf(v.z); o.w = f2bf(v.w);
        *(ushort4*)(xb + i) = o;
        return;
    }
    __shared__ float T[64][68];
    const float* in; unsigned short* out; int N, k0, n0;
    if (bx < 8192 + 768) {
        int t = bx - 8192;
        in = Wa; out = Wat; N = 3 * CDIM;
        n0 = (t % 48) * 64; k0 = (t / 48) * 64;
    } else {
        int t = bx - 8960;
        in = Wp; out = Wpt; N = CDIM;
        n0 = (t & 15) * 64; k0 = (t >> 4) * 64;
    }
    const int K = CDIM;
    const int r = tid >> 4, c4 = (tid & 15) * 4;
    #pragma unroll
    for (int i = 0; i < 4; ++i) {
        int row = r + i * 16;
        float4 v = *(const float4*)(in + (size_t)(k0 + row) * N + n0 + c4);
        T[row][c4 + 0] = v.x; T[row][c4 + 1] = v.y;
        T[row][c4 + 2] = v.z; T[row][c4 + 3] = v.w;
    }
    __syncthreads();
    #pragma unroll
    for (int i = 0; i < 4; ++i) {
        int nrow = r + i * 16;
        ushort4 o;
        o.x = f2bf(T[c4 + 0][nrow]); o.y = f2bf(T[c4 + 1][nrow]);
        o.z = f2bf(T[c4 + 2][nrow]); o.w = f2bf(T[c4 + 3][nrow]);
        *(ushort4*)(out + (size_t)(n0 + nrow) * K + k0 + c4) = o;
    }
}

// ---------------------------------------------------------------------------
// QKV GEMM: 256x256 tile, BK=64, 512 thr = 8 waves (2M x 4N), 8-phase
// schedule with counted vmcnt (symmetric stage: 2 loads/thread per half;
// waits 4,4,4,4 - race-screened in rounds 1/3/4/6), LDS XOR-chunk swizzle
// (global-source side), setprio around each 16-MFMA cluster.
// Grid: 384 blocks 1D with XCD-aware bijective swizzle (384 % 8 == 0).
// ---------------------------------------------------------------------------
__global__ __launch_bounds__(512, 2) void qkv_mfma_kernel(
    const unsigned short* __restrict__ A,    // xb [8192][1024]
    const unsigned short* __restrict__ Bt,   // Wat [3072][1024]
    const float* __restrict__ bias,          // [3072]
    unsigned short* __restrict__ Qo,         // [BH][T][64]
    unsigned short* __restrict__ Ko,         // [BH][T][64]
    unsigned short* __restrict__ Vo)         // [BH][64][T]
{
    __shared__ __align__(16) unsigned short L[2 * 32768];   // 128 KB

    const int tid = threadIdx.x;
    // XCD swizzle: XCD c owns flat%8==c; its blocks walk tiles contiguously.
    const int flat = blockIdx.x;
    const int swz = (flat & 7) * 48 + (flat >> 3);
    const int m0 = (swz / 12) * 256, n0 = (swz % 12) * 256;
    const int w = tid >> 6, lane = tid & 63;
    const int wr = w >> 2, wc = w & 3;        // 2M x 4N
    const int lm = lane & 15, kg = lane >> 4;
    const int sw = lm & 7;                    // read-side XOR swizzle key

    floatx4 acc[2][4][2][2];
    const floatx4 zf = {0.f, 0.f, 0.f, 0.f};
    #pragma unroll
    for (int a = 0; a < 2; ++a)
        #pragma unroll
        for (int b = 0; b < 4; ++b)
            #pragma unroll
            for (int c = 0; c < 2; ++c)
                #pragma unroll
                for (int d = 0; d < 2; ++d) acc[a][b][c][d] = zf;

    short8 af[4][2], bf[2][2];

#define QSTAGE_A(B_, H_, KT_) do {                                            \
    unsigned short* _l = (unsigned short*)L + (B_) * 32768 + (H_) * 8192;     \
    _Pragma("unroll")                                                         \
    for (int _i = 0; _i < 2; ++_i) {                                          \
        int _s = _i * 512 + tid, _r = _s >> 3, _c = _s & 7;                   \
        GLOAD16(A + (size_t)(m0 + (H_) * 128 + _r) * CDIM + (KT_) * 64        \
                   + ((_c ^ (_r & 7)) * 8), _l + _s * 8);                     \
    } } while (0)

#define QSTAGE_B(B_, H_, KT_) do {                                            \
    unsigned short* _l = (unsigned short*)L + (B_) * 32768 + 16384 + (H_) * 8192; \
    _Pragma("unroll")                                                         \
    for (int _i = 0; _i < 2; ++_i) {                                          \
        int _s = _i * 512 + tid, _r = _s >> 3, _c = _s & 7;                   \
        GLOAD16(Bt + (size_t)(n0 + (H_) * 128 + _r) * CDIM + (KT_) * 64       \
                   + ((_c ^ (_r & 7)) * 8), _l + _s * 8);                     \
    } } while (0)

#define QLOAD_A(B_, H_) do {                                                  \
    const unsigned short* _p = (const unsigned short*)L + (B_) * 32768 + (H_) * 8192; \
    _Pragma("unroll")                                                         \
    for (int _m = 0; _m < 4; ++_m) {                                          \
        int _row = wr * 64 + _m * 16 + lm;                                    \
        _Pragma("unroll")                                                     \
        for (int _k = 0; _k < 2; ++_k)                                        \
            af[_m][_k] = *(const short8*)(_p + _row * 64                      \
                          + (((_k * 4 + kg) ^ sw) * 8));                      \
    } } while (0)

#define QLOAD_B(B_, H_) do {                                                  \
    const unsigned short* _p = (const unsigned short*)L + (B_) * 32768 + 16384 + (H_) * 8192; \
    _Pragma("unroll")                                                         \
    for (int _n = 0; _n < 2; ++_n) {                                          \
        int _row = wc * 32 + _n * 16 + lm;                                    \
        _Pragma("unroll")                                                     \
        for (int _k = 0; _k < 2; ++_k)                                        \
            bf[_n][_k] = *(const short8*)(_p + _row * 64                      \
                          + (((_k * 4 + kg) ^ sw) * 8));                      \
    } } while (0)

#define QMFMA(HH_, HP_) do {                                                  \
    _Pragma("unroll") for (int _k = 0; _k < 2; ++_k)                          \
    _Pragma("unroll") for (int _m = 0; _m < 4; ++_m)                          \
    _Pragma("unroll") for (int _n = 0; _n < 2; ++_n)                          \
        acc[HH_][_m][HP_][_n] =                                               \
            MFMA_BF16(af[_m][_k], bf[_n][_k], acc[HH_][_m][HP_][_n]);         \
    } while (0)

#define QPHASE(HH_, HP_, LA_, LB_, STAGE_, VM_) do {                          \
    if (LA_) QLOAD_A(buf, HH_);                                               \
    if (LB_) QLOAD_B(buf, HP_);                                               \
    STAGE_;                                                                   \
    asm volatile("s_waitcnt vmcnt(" #VM_ ")" ::: "memory");                   \
    __builtin_amdgcn_s_barrier();                                             \
    asm volatile("s_waitcnt lgkmcnt(0)" ::: "memory");                        \
    __builtin_amdgcn_sched_barrier(0);                                        \
    __builtin_amdgcn_s_setprio(1);                                            \
    QMFMA(HH_, HP_);                                                          \
    __builtin_amdgcn_s_setprio(0);                                            \
    __builtin_amdgcn_s_barrier();                                             \
    __builtin_amdgcn_sched_barrier(0);                                        \
    } while (0)

    // prologue: tile 0, halves in first-use order; drain to 4 -> A0,B0 landed
    QSTAGE_A(0, 0, 0); QSTAGE_B(0, 0, 0); QSTAGE_B(0, 1, 0); QSTAGE_A(0, 1, 0);
    asm volatile("s_waitcnt vmcnt(4)" ::: "memory");
    __builtin_amdgcn_s_barrier();

    #pragma unroll 1
    for (int t = 0; t < CDIM / 64 - 1; ++t) {
        const int buf = t & 1, nb = buf ^ 1;
        QPHASE(0, 0, 1, 1, QSTAGE_A(nb, 0, t + 1), 4);
        QPHASE(0, 1, 0, 1, QSTAGE_B(nb, 0, t + 1), 4);
        QPHASE(1, 1, 1, 0, QSTAGE_B(nb, 1, t + 1), 4);
        QPHASE(1, 0, 0, 1, QSTAGE_A(nb, 1, t + 1), 4);
    }
    {   // last tile: no staging; drain 2 -> 0
        const int buf = (CDIM / 64 - 1) & 1;
        QPHASE(0, 0, 1, 1, ((void)0), 2);
        QPHASE(0, 1, 0, 1, ((void)0), 0);
        QPHASE(1, 1, 1, 0, ((void)0), 0);
        QPHASE(1, 0, 0, 1, ((void)0), 0);
    }

#undef QPHASE
#undef QMFMA
#undef QLOAD_B
#undef QLOAD_A
#undef QSTAGE_B
#undef QSTAGE_A

    // epilogue: C frag (hh,mt,hp,nt): row = m0+hh*128+wr*64+mt*16+kg*4+r,
    //                                 col = n0+hp*128+wc*32+nt*16+lm
    #pragma unroll
    for (int hp = 0; hp < 2; ++hp) {
        #pragma unroll
        for (int nt = 0; nt < 2; ++nt) {
            int col = n0 + hp * 128 + wc * 32 + nt * 16 + lm;
            float bv = bias[col];
            int which = col >> 10;
            int c1 = col & 1023;
            int h = c1 >> 6, d = c1 & 63;
            #pragma unroll
            for (int hh = 0; hh < 2; ++hh) {
                #pragma unroll
                for (int mt = 0; mt < 4; ++mt) {
                    int m = m0 + hh * 128 + wr * 64 + mt * 16 + kg * 4;
                    int b = m >> 11;
                    int tt = m & 2047;           // tt..tt+3 contiguous
                    int bh = b * NHEAD + h;
                    floatx4 a = acc[hh][mt][hp][nt];
                    if (which == 2) {
                        ushort4 o;
                        o.x = f2bf(a[0] + bv);
                        o.y = f2bf(a[1] + bv);
                        o.z = f2bf(a[2] + bv);
                        o.w = f2bf(a[3] + bv);
                        *(ushort4*)(Vo + ((size_t)bh * 64 + d) * SEQ + tt) = o;
                    } else {
                        unsigned short* dst = (which == 0) ? Qo : Ko;
                        float qs = (which == 0) ? 0.18033688011112042f : 1.0f;
                        #pragma unroll
                        for (int r = 0; r < 4; ++r)
                            dst[((size_t)bh * SEQ + tt + r) * 64 + d] =
                                f2bf((a[r] + bv) * qs);
                    }
                }
            }
        }
    }
}

// ---------------------------------------------------------------------------
// Proj GEMM: proven 128x128 2-phase (512 blocks, good fill).
// ---------------------------------------------------------------------------
#define GBUF (128 * 32)   // shorts per operand buffer

__device__ __forceinline__ void gemm_stage(
    const unsigned short* __restrict__ A, const unsigned short* __restrict__ Bt,
    int K, int m0, int n0, int k0, unsigned short* As, unsigned short* Bs, int tid)
{
    #pragma unroll
    for (int i = 0; i < 2; ++i) {
        int ci = i * 256 + tid;                 // 0..511
        GLOAD16(A  + (size_t)(m0 + (ci >> 2)) * K + k0 + (ci & 3) * 8, As + ci * 8);
        GLOAD16(Bt + (size_t)(n0 + (ci >> 2)) * K + k0 + (ci & 3) * 8, Bs + ci * 8);
    }
}

__global__ __launch_bounds__(256) void proj_mfma_kernel(
    const unsigned short* __restrict__ A,
    const unsigned short* __restrict__ Bt,
    const float* __restrict__ bias,
    float* __restrict__ out)
{
    const int K = CDIM;
    __shared__ __align__(16) unsigned short As2[2 * GBUF];
    __shared__ __align__(16) unsigned short Bs2[2 * GBUF];

    const int tid = threadIdx.x;
    const int m0 = blockIdx.y * 128, n0 = blockIdx.x * 128;
    const int w = tid >> 6, lane = tid & 63;
    const int wm = (w >> 1) * 64, wn = (w & 1) * 64;
    const int lm = lane & 15, kg = lane >> 4;

    floatx4 acc[4][4];
    const floatx4 zf = {0.f, 0.f, 0.f, 0.f};
    #pragma unroll
    for (int mt = 0; mt < 4; ++mt)
        #pragma unroll
        for (int nt = 0; nt < 4; ++nt) acc[mt][nt] = zf;

    gemm_stage(A, Bt, K, m0, n0, 0, As2, Bs2, tid);

    #pragma unroll 1
    for (int kt = 0; kt < K / 32; ++kt) {
        __syncthreads();
        if (kt + 1 < K / 32)
            gemm_stage(A, Bt, K, m0, n0, (kt + 1) * 32,
                       As2 + ((kt + 1) & 1) * GBUF, Bs2 + ((kt + 1) & 1) * GBUF, tid);
        const unsigned short* As = As2 + (kt & 1) * GBUF;
        const unsigned short* Bs = Bs2 + (kt & 1) * GBUF;
        short8 af[4], bfr[4];
        #pragma unroll
        for (int t = 0; t < 4; ++t) {
            af[t]  = *(const short8*)(As + (wm + t * 16 + lm) * 32 + kg * 8);
            bfr[t] = *(const short8*)(Bs + (wn + t * 16 + lm) * 32 + kg * 8);
        }
        #pragma unroll
        for (int mt = 0; mt < 4; ++mt)
            #pragma unroll
            for (int nt = 0; nt < 4; ++nt)
                acc[mt][nt] = MFMA_BF16(af[mt], bfr[nt], acc[mt][nt]);
    }

    #pragma unroll
    for (int nt = 0; nt < 4; ++nt) {
        int col = n0 + wn + nt * 16 + lm;
        float bv = bias[col];
        #pragma unroll
        for (int mt = 0; mt < 4; ++mt) {
            int mbase = m0 + wm + mt * 16 + kg * 4;
            #pragma unroll
            for (int r = 0; r < 4; ++r)
                out[(size_t)(mbase + r) * CDIM + col] = acc[mt][nt][r] + bv;
        }
    }
}

// ---------------------------------------------------------------------------
// Flash attention (round-4/6 version, verified passing at ~81 us):
// 256 thr = 4 waves x 32 q-rows, 128 q-rows/block, grid 16x64; P in
// registers via K-row permutation on the global address side; XOR chunk
// swizzle; dbuf async staging, one barrier per tile; fp32 VALU row sums +
// epilogue shuffle reduce (proven numerics).
// Q,K: [BH][T][64] bf16 (Q pre-scaled); V: [BH][64][T] bf16. Y: [B][T][C] bf16.
// ---------------------------------------------------------------------------
#define BUFSH 8192   // shorts per LDS buffer: K 4096 + V 4096

__device__ __forceinline__ void attn_stage_tile(
    const unsigned short* __restrict__ Kg,
    const unsigned short* __restrict__ Vg,
    size_t base, int kb, unsigned short* buf, int tid)
{
    unsigned short* Kb_ = buf;
    unsigned short* Vb_ = buf + 4096;
    #pragma unroll
    for (int i = 0; i < 2; ++i) {
        int lin = i * 256 + tid;          // 0..511 (16B slots)
        int srow = lin >> 3;              // 0..63
        int chunk = lin & 7;
        int s2 = srow & 31;
        // inverse of the k-permutation: srow2 = mt*16+kg*4+r holds k' = kg*8+mt*4+r
        int grow = (srow & 32) + ((s2 >> 2) & 3) * 8 + ((s2 >> 4) & 1) * 4 + (s2 & 3);
        int gch = chunk ^ (srow & 7);     // XOR swizzle, within-row
        GLOAD16(Kg + base + (size_t)(kb * 64 + grow) * 64 + gch * 8, Kb_ + lin * 8);
        GLOAD16(Vg + base + (size_t)srow * SEQ + kb * 64 + gch * 8, Vb_ + lin * 8);
    }
}

__global__ __launch_bounds__(256) void attn_mfma_kernel(
    const unsigned short* __restrict__ Qg,
    const unsigned short* __restrict__ Kg,
    const unsigned short* __restrict__ Vg,
    unsigned short* __restrict__ Y)
{
    __shared__ __align__(16) unsigned short Smem[2 * BUFSH];   // 32 KB

    const int tid = threadIdx.x, w = tid >> 6, lane = tid & 63;
    const int lm = lane & 15, kg = lane >> 4;
    const int qb = blockIdx.x, bh = blockIdx.y;
    const size_t base = (size_t)bh * SEQ * 64;

    // Q frags in registers: q = qb*128 + w*32 + nt*16 + lm
    short8 qf[2][2];
    #pragma unroll
    for (int nt = 0; nt < 2; ++nt)
        #pragma unroll
        for (int c = 0; c < 2; ++c)
            qf[nt][c] = *(const short8*)(
                Qg + base + (size_t)(qb * 128 + w * 32 + nt * 16 + lm) * 64 + c * 32 + kg * 8);

    const floatx4 zf = {0.f, 0.f, 0.f, 0.f};
    floatx4 O[2][4];     // [q-tile][d-tile]
    #pragma unroll
    for (int nt = 0; nt < 2; ++nt)
        #pragma unroll
        for (int nd = 0; nd < 4; ++nd) O[nt][nd] = zf;
    float lsum[2] = {0.f, 0.f};

    // prologue: stage tile 0 into buffer 0
    attn_stage_tile(Kg, Vg, base, 0, Smem, tid);

    #pragma unroll 1
    for (int kb = 0; kb < SEQ / 64; ++kb) {
        __syncthreads();   // drains vmcnt(0): buffer kb&1 is ready
        if (kb + 1 < SEQ / 64)
            attn_stage_tile(Kg, Vg, base, kb + 1, Smem + ((kb + 1) & 1) * BUFSH, tid);

        const unsigned short* Ksb = Smem + (kb & 1) * BUFSH;
        const unsigned short* Vsb = Ksb + 4096;
        const int sw = (lm & 7);   // XOR swizzle key for this lane's rows

        // two 32-k chunks; P built entirely in registers
        #pragma unroll
        for (int ch = 0; ch < 2; ++ch) {
            uint4 pa[2];   // PV A-frags (8 bf16 per lane per q-tile)
            #pragma unroll
            for (int mt = 0; mt < 2; ++mt) {
                floatx4 st[2];
                #pragma unroll
                for (int nt = 0; nt < 2; ++nt) st[nt] = zf;
                #pragma unroll
                for (int c = 0; c < 2; ++c) {
                    short8 kf = *(const short8*)(
                        Ksb + (ch * 32 + mt * 16 + lm) * 64 + ((c * 4 + kg) ^ sw) * 8);
                    #pragma unroll
                    for (int nt = 0; nt < 2; ++nt)
                        st[nt] = MFMA_BF16(kf, qf[nt][c], st[nt]);
                }
                #pragma unroll
                for (int nt = 0; nt < 2; ++nt) {
                    float e0 = fast_exp2(st[nt][0]);
                    float e1 = fast_exp2(st[nt][1]);
                    float e2 = fast_exp2(st[nt][2]);
                    float e3 = fast_exp2(st[nt][3]);
                    lsum[nt] += (e0 + e1) + (e2 + e3);
                    if (mt == 0) {
                        pa[nt].x = pack_bf16_trunc(e0, e1);
                        pa[nt].y = pack_bf16_trunc(e2, e3);
                    } else {
                        pa[nt].z = pack_bf16_trunc(e0, e1);
                        pa[nt].w = pack_bf16_trunc(e2, e3);
                    }
                }
            }
            // PV over this 32-k chunk
            #pragma unroll
            for (int nd = 0; nd < 4; ++nd) {
                short8 vb = *(const short8*)(
                    Vsb + (nd * 16 + lm) * 64 + ((ch * 4 + kg) ^ sw) * 8);
                #pragma unroll
                for (int nt = 0; nt < 2; ++nt) {
                    short8 paf;
                    __builtin_memcpy(&paf, &pa[nt], 16);
                    O[nt][nd] = MFMA_BF16(paf, vb, O[nt][nd]);
                }
            }
        }
    }

    // finalize row sums (kg lanes hold disjoint k subsets)
    #pragma unroll
    for (int nt = 0; nt < 2; ++nt) {
        lsum[nt] += __shfl_xor(lsum[nt], 16);
        lsum[nt] += __shfl_xor(lsum[nt], 32);
    }
    float linv[2][4];
    #pragma unroll
    for (int mq = 0; mq < 2; ++mq)
        #pragma unroll
        for (int r = 0; r < 4; ++r)
            linv[mq][r] = 1.0f / __shfl(lsum[mq], kg * 4 + r);

    // epilogue: Y[b][t][h*64 + d] bf16
    const int b = bh >> 4, h = bh & 15;
    #pragma unroll
    for (int mq = 0; mq < 2; ++mq)
        #pragma unroll
        for (int r = 0; r < 4; ++r) {
            int t = qb * 128 + w * 32 + mq * 16 + kg * 4 + r;
            #pragma unroll
            for (int nd = 0; nd < 4; ++nd)
                Y[((size_t)(b * SEQ + t)) * CDIM + h * 64 + nd * 16 + lm] =
                    f2bf(O[mq][nd][r] * linv[mq][r]);
        }
}

extern "C" void kernel_launch(void* const* d_in, const int* in_sizes, int n_in,
                              void* d_out, int out_size, void* d_ws, size_t ws_size,
                              hipStream_t stream) {
    const float* x      = (const float*)d_in[0];
    const float* W_attn = (const float*)d_in[1];
    const float* b_attn = (const float*)d_in[2];
    const float* W_proj = (const float*)d_in[3];
    const float* b_proj = (const float*)d_in[4];
    float* out = (float*)d_out;

    // workspace layout (bf16 buffers)
    char* ws = (char*)d_ws;
    unsigned short* xb  = (unsigned short*)(ws);                      // 16.8 MB
    unsigned short* Wat = (unsigned short*)(ws + (size_t)16777216);   //  6.3 MB
    unsigned short* Wpt = (unsigned short*)(ws + (size_t)23068672);   //  2.1 MB
    unsigned short* Qb  = (unsigned short*)(ws + (size_t)25165824);   // 16.8 MB
    unsigned short* Kb  = (unsigned short*)(ws + (size_t)41943040);   // 16.8 MB
    unsigned short* Vtb = (unsigned short*)(ws + (size_t)58720256);   // 16.8 MB
    unsigned short* Yb  = (unsigned short*)(ws + (size_t)75497472);   // 16.8 MB

    // all converts in one launch: 8192 (x) + 768 (W_attn) + 256 (W_proj)
    conv_all_kernel<<<dim3(9216), 256, 0, stream>>>(
        x, xb, W_attn, Wat, W_proj, Wpt);

    // QKV projection: 256x256 8-phase, 384 blocks, XCD-swizzled 1D grid
    qkv_mfma_kernel<<<dim3(384), 512, 0, stream>>>(
        xb, Wat, b_attn, Qb, Kb, Vtb);

    // attention: 128 q-rows per block, 4 waves x 32 q-rows, dbuf async staging
    attn_mfma_kernel<<<dim3(SEQ / 128, BH), 256, 0, stream>>>(Qb, Kb, Vtb, Yb);

    // output projection: 128x128 2-phase MFMA GEMM (512 blocks, good fill)
    proj_mfma_kernel<<<dim3(CDIM / 128, MROWS / 128), 256, 0, stream>>>(
        Yb, Wpt, b_proj, out);
}